// Round 3
// baseline (1128.857 us; speedup 1.0000x reference)
//
#include <hip/hip_runtime.h>

typedef unsigned short u16;
typedef unsigned int   u32;

#define N_PTS   131072
#define M_PTS   32768
#define BNCF    0.9999950000374997f

__device__ __forceinline__ float b2f(u16 u) {
    u32 x = ((u32)u) << 16;
    float f;
    __builtin_memcpy(&f, &x, 4);
    return f;
}
__device__ __forceinline__ u16 f2b(float f) {
    u32 x;
    __builtin_memcpy(&x, &f, 4);
    u32 r = x + 0x7fffu + ((x >> 16) & 1u);
    return (u16)(r >> 16);
}
__device__ __forceinline__ float silu_f(float x) {
    return x / (1.0f + __expf(-x));
}

// ---------------------------------------------------------------- centers
__global__ __launch_bounds__(256) void k_centers(const float* __restrict__ pos,
                                                 const float* __restrict__ sfv,
                                                 const int* __restrict__ batch,
                                                 float* __restrict__ acc) {
    __shared__ float ls[16];
    int t = threadIdx.x;
    if (t < 16) ls[t] = 0.0f;
    __syncthreads();
    int i = blockIdx.x * 256 + t;
    if (i < N_PTS) {
        int b = batch[i];
        float inv = 1.0f / sfv[b];
        atomicAdd(&ls[b * 4 + 0], pos[i * 3 + 0] * inv);
        atomicAdd(&ls[b * 4 + 1], pos[i * 3 + 1] * inv);
        atomicAdd(&ls[b * 4 + 2], pos[i * 3 + 2] * inv);
        atomicAdd(&ls[b * 4 + 3], 1.0f);
    }
    __syncthreads();
    if (t < 16) atomicAdd(&acc[t], ls[t]);
}

// ---------------------------------------------------------------- stem
__global__ __launch_bounds__(128) void k_stem(const float* __restrict__ pos,
                                              const float* __restrict__ refl,
                                              const float* __restrict__ sfv,
                                              const int* __restrict__ batch,
                                              const float* __restrict__ cacc,
                                              const float* __restrict__ g,
                                              const float* __restrict__ bb,
                                              const float* __restrict__ w1,
                                              const float* __restrict__ b1,
                                              const float* __restrict__ w2,
                                              const float* __restrict__ b2,
                                              u16* __restrict__ xout) {
    __shared__ float xin[128 * 98];
    const float FREQS[16] = {
        1.0f, 0.31622776601683794f, 0.1f, 0.031622776601683791f,
        0.01f, 0.0031622776601683794f, 0.001f, 0.00031622776601683794f,
        0.0001f, 3.1622776601683795e-05f, 1e-05f, 3.1622776601683796e-06f,
        1e-06f, 3.1622776601683797e-07f, 1e-07f, 3.1622776601683792e-08f};
    int t = threadIdx.x;
    int i = blockIdx.x * 128 + t;
    float* xr = &xin[t * 98];

    int b = batch[i];
    float s = 1.0f / sfv[b];
    float cnt = fmaxf(cacc[b * 4 + 3], 1.0f);
    float npv[3];
#pragma unroll
    for (int d = 0; d < 3; ++d)
        npv[d] = pos[i * 3 + d] * s - cacc[b * 4 + d] / cnt;

#pragma unroll
    for (int d = 0; d < 3; ++d) {
#pragma unroll
        for (int f = 0; f < 16; ++f) {
            float a = npv[d] * FREQS[f];
            float sv, cv;
            __sincosf(a, &sv, &cv);
            xr[d * 32 + f] = sv;
            xr[d * 32 + 16 + f] = cv;
        }
    }
    xr[96] = refl[i];

    float sum = 0.0f, sq = 0.0f;
    for (int k = 0; k < 97; ++k) {
        float v = xr[k];
        sum += v;
        sq += v * v;
    }
    float m = sum * (1.0f / 97.0f);
    float var = sq * (1.0f / 97.0f) - m * m;
    float rstd = rsqrtf(fmaxf(var, 0.0f) + 1e-5f);
    for (int k = 0; k < 97; ++k)
        xr[k] = (xr[k] - m) * rstd * g[k] + bb[k];

    float acc[32];
#pragma unroll
    for (int o = 0; o < 32; ++o) acc[o] = 0.0f;

    for (int j0 = 0; j0 < 64; j0 += 4) {
        float h0 = b1[j0 + 0], h1 = b1[j0 + 1];
        float h2 = b1[j0 + 2], h3 = b1[j0 + 3];
        for (int k = 0; k < 97; ++k) {
            float v = xr[k];
            const float* wp = w1 + k * 64 + j0;
            h0 += v * wp[0];
            h1 += v * wp[1];
            h2 += v * wp[2];
            h3 += v * wp[3];
        }
        float hh[4] = {h0, h1, h2, h3};
#pragma unroll
        for (int jj = 0; jj < 4; ++jj) {
            float hs = silu_f(BNCF * hh[jj]);
            const float* w2p = w2 + (j0 + jj) * 32;
#pragma unroll
            for (int o = 0; o < 32; ++o) acc[o] += hs * w2p[o];
        }
    }
    u16* xo = xout + (long)i * 32;
#pragma unroll
    for (int o = 0; o < 32; ++o)
        xo[o] = f2b(silu_f(BNCF * (acc[o] + b2[o])));
}

// ---------------------------------------------------------------- sfeat
__global__ __launch_bounds__(256) void k_sfeat(const float* __restrict__ pos,
                                               const int* __restrict__ idxp,
                                               const int* __restrict__ colp,
                                               const float* __restrict__ lkw,
                                               const float* __restrict__ lkb,
                                               const float* __restrict__ lng,
                                               const float* __restrict__ lnb,
                                               float* __restrict__ sfeat) {
    int r = blockIdx.x * 256 + threadIdx.x;
    if (r >= M_PTS) return;
    int ci = idxp[r];
    float cx = pos[ci * 3 + 0];
    float cy = pos[ci * 3 + 1];
    float cz = pos[ci * 3 + 2];
    float dsx = 0.0f, dsy = 0.0f, dsz = 0.0f;
    for (int e = 0; e < 16; ++e) {
        int c = colp[r * 16 + e];
        float dx = pos[c * 3 + 0] - cx;
        float dy = pos[c * 3 + 1] - cy;
        float dz = pos[c * 3 + 2] - cz;
        float nrm = sqrtf(dx * dx + dy * dy + dz * dz);
        float inv = 1.0f / (nrm + 1e-8f);
        dsx += dx * inv;
        dsy += dy * inv;
        dsz += dz * inv;
    }
    const float S3 = 0.57735026918962576f;
    const float sx[8] = {1, -1, 1, 1, -1, -1, 1, -1};
    const float sy[8] = {1, 1, -1, 1, -1, 1, -1, -1};
    const float sz[8] = {1, 1, 1, -1, 1, -1, -1, -1};
    float sc[3] = {lkb[0], lkb[1], lkb[2]};
#pragma unroll
    for (int j = 0; j < 8; ++j) {
        float nb = (sx[j] * dsx + sy[j] * dsy + sz[j] * dsz) * (S3 * (1.0f / 16.0f));
        sc[0] += nb * lkw[j * 3 + 0];
        sc[1] += nb * lkw[j * 3 + 1];
        sc[2] += nb * lkw[j * 3 + 2];
    }
    float m = (sc[0] + sc[1] + sc[2]) * (1.0f / 3.0f);
    float v = ((sc[0] - m) * (sc[0] - m) + (sc[1] - m) * (sc[1] - m) +
               (sc[2] - m) * (sc[2] - m)) * (1.0f / 3.0f);
    float rstd = rsqrtf(fmaxf(v, 0.0f) + 1e-5f);
#pragma unroll
    for (int c = 0; c < 3; ++c)
        sfeat[r * 3 + c] = (sc[c] - m) * rstd * lng[c] + lnb[c];
}

// ---------------------------------------------------------------- edge MLP + segment max
__global__ __launch_bounds__(256) void k_edge(const float* __restrict__ pos,
                                              const float* __restrict__ refl,
                                              const int* __restrict__ idxp,
                                              const int* __restrict__ colp,
                                              const u16* __restrict__ xfeat,
                                              const float* __restrict__ sfeat,
                                              const float* __restrict__ w1,
                                              const float* __restrict__ b1,
                                              const float* __restrict__ w2,
                                              const float* __restrict__ b2,
                                              float* __restrict__ agg) {
    __shared__ float uni[8192];       // msg [128][41] then w2 [64*128]
    __shared__ u16 hbuf[128 * 65];    // bf16 hidden
    __shared__ float w1s[39 * 64];
    __shared__ float b1s[64];
    __shared__ float b2s[128];
    int t = threadIdx.x;
    int r0 = blockIdx.x * 8;
    long e0 = (long)r0 * 16;

    for (int u = t; u < 39 * 64; u += 256) w1s[u] = w1[u];
    if (t < 64) b1s[t] = b1[t];
    if (t < 128) b2s[t] = b2[t];

    for (int u = t; u < 128 * 4; u += 256) {
        int e = u >> 2, seg = u & 3;
        int c = colp[e0 + e];
        uint4 d = *(const uint4*)(xfeat + (long)c * 32 + seg * 8);
        float* mp = &uni[e * 41 + seg * 8];
        u32 ws_[4] = {d.x, d.y, d.z, d.w};
#pragma unroll
        for (int q = 0; q < 4; ++q) {
            mp[q * 2 + 0] = b2f((u16)(ws_[q] & 0xffffu));
            mp[q * 2 + 1] = b2f((u16)(ws_[q] >> 16));
        }
    }
    if (t < 128) {
        int e = t;
        int r = r0 + (e >> 4);
        int c = colp[e0 + e];
        int ci = idxp[r];
        float* mp = &uni[e * 41];
        mp[32] = pos[c * 3 + 0] - pos[ci * 3 + 0];
        mp[33] = pos[c * 3 + 1] - pos[ci * 3 + 1];
        mp[34] = pos[c * 3 + 2] - pos[ci * 3 + 2];
        mp[35] = refl[c] - refl[ci];
        mp[36] = sfeat[r * 3 + 0];
        mp[37] = sfeat[r * 3 + 1];
        mp[38] = sfeat[r * 3 + 2];
    }
    __syncthreads();

    {
        int q = t & 31;
        int j0 = (t >> 5) * 8;
        float acc[4][8];
#pragma unroll
        for (int i = 0; i < 4; ++i)
#pragma unroll
            for (int jj = 0; jj < 8; ++jj) acc[i][jj] = b1s[j0 + jj];
        for (int k = 0; k < 39; ++k) {
            float a0 = uni[(q + 0) * 41 + k];
            float a1 = uni[(q + 32) * 41 + k];
            float a2 = uni[(q + 64) * 41 + k];
            float a3 = uni[(q + 96) * 41 + k];
#pragma unroll
            for (int jj = 0; jj < 8; ++jj) {
                float w = w1s[k * 64 + j0 + jj];
                acc[0][jj] += a0 * w;
                acc[1][jj] += a1 * w;
                acc[2][jj] += a2 * w;
                acc[3][jj] += a3 * w;
            }
        }
#pragma unroll
        for (int i = 0; i < 4; ++i)
#pragma unroll
            for (int jj = 0; jj < 8; ++jj)
                hbuf[(q + 32 * i) * 65 + j0 + jj] =
                    f2b(silu_f(BNCF * acc[i][jj]));
    }
    __syncthreads();

    for (int u = t; u < 64 * 128; u += 256) uni[u] = w2[u];
    __syncthreads();

    {
        int rl = t >> 5;
        int o0 = t & 31;
        float acc[16][4];
#pragma unroll
        for (int e = 0; e < 16; ++e)
#pragma unroll
            for (int j = 0; j < 4; ++j) acc[e][j] = b2s[o0 + 32 * j];
        for (int k = 0; k < 64; ++k) {
            float wv[4];
#pragma unroll
            for (int j = 0; j < 4; ++j) wv[j] = uni[k * 128 + o0 + 32 * j];
#pragma unroll
            for (int e = 0; e < 16; ++e) {
                float hv = b2f(hbuf[(rl * 16 + e) * 65 + k]);
                acc[e][0] += hv * wv[0];
                acc[e][1] += hv * wv[1];
                acc[e][2] += hv * wv[2];
                acc[e][3] += hv * wv[3];
            }
        }
        int rg = r0 + rl;
#pragma unroll
        for (int j = 0; j < 4; ++j) {
            float mx = -1e30f;
#pragma unroll
            for (int e = 0; e < 16; ++e) {
                float v = silu_f(BNCF * acc[e][j]);
                mx = fmaxf(mx, v);
            }
            agg[(long)rg * 128 + o0 + 32 * j] = mx;
        }
    }
}

// ---------------------------------------------------------------- fused GEMM (vector f32)
// 128x64 tile, 8x4 micro-tile. AMODE: 0=f32 A, 1=bf16 A. EPI: epilogue.
// OD: 0 = bf16 output, 1 = f32 output.
template <int AMODE, int EPI, int OD>
__global__ __launch_bounds__(256) void k_gemm(const void* __restrict__ Av,
                                              const float* __restrict__ W,
                                              const float* __restrict__ bias,
                                              const float* __restrict__ dww,
                                              const float* __restrict__ dwb,
                                              const float* __restrict__ res,
                                              void* __restrict__ Ov,
                                              int K, int Nn) {
    __shared__ float As[128 * 20];
    __shared__ float Ws[16 * 68];
    int t = threadIdx.x;
    int tr = t >> 4, tc = t & 15;
    int R0 = blockIdx.y * 128, C0 = blockIdx.x * 64;
    float acc[8][4];
#pragma unroll
    for (int i = 0; i < 8; ++i)
#pragma unroll
        for (int j = 0; j < 4; ++j) acc[i][j] = 0.0f;

    for (int k0 = 0; k0 < K; k0 += 16) {
        if (AMODE == 0) {
            const float* A = (const float*)Av;
            for (int u = t; u < 512; u += 256) {
                int row = u >> 2, k4 = (u & 3) * 4;
                float4 v = *(const float4*)(A + (long)(R0 + row) * K + k0 + k4);
                float* dst = &As[row * 20 + k4];
                dst[0] = v.x; dst[1] = v.y; dst[2] = v.z; dst[3] = v.w;
            }
        } else {
            const u16* A = (const u16*)Av;
            for (int u = t; u < 512; u += 256) {
                int row = u >> 2, k4 = (u & 3) * 4;
                ushort4 v = *(const ushort4*)(A + (long)(R0 + row) * K + k0 + k4);
                float* dst = &As[row * 20 + k4];
                dst[0] = b2f(v.x); dst[1] = b2f(v.y);
                dst[2] = b2f(v.z); dst[3] = b2f(v.w);
            }
        }
        {
            int kk = t >> 4, c4 = (t & 15) * 4;
            float4 v = *(const float4*)(W + (long)(k0 + kk) * Nn + C0 + c4);
            float* dst = &Ws[kk * 68 + c4];
            dst[0] = v.x; dst[1] = v.y; dst[2] = v.z; dst[3] = v.w;
        }
        __syncthreads();
#pragma unroll
        for (int kk = 0; kk < 16; ++kk) {
            float a[8], w[4];
#pragma unroll
            for (int i = 0; i < 8; ++i) a[i] = As[(tr + 16 * i) * 20 + kk];
#pragma unroll
            for (int j = 0; j < 4; ++j) w[j] = Ws[kk * 68 + tc + 16 * j];
#pragma unroll
            for (int i = 0; i < 8; ++i)
#pragma unroll
                for (int j = 0; j < 4; ++j) acc[i][j] += a[i] * w[j];
        }
        __syncthreads();
    }
#pragma unroll
    for (int i = 0; i < 8; ++i) {
        int row = R0 + tr + 16 * i;
#pragma unroll
        for (int j = 0; j < 4; ++j) {
            int col = C0 + tc + 16 * j;
            float v = acc[i][j];
            if (EPI == 0) {
                v = silu_f(BNCF * (v + bias[col]));
                v = silu_f(BNCF * (v * dww[col] + dwb[col]));
            } else if (EPI == 1) {
                v = silu_f(BNCF * (v + bias[col]));
                v = silu_f(BNCF * v);
                v = silu_f(BNCF * (v * dww[col] + dwb[col]));
            } else if (EPI == 2) {
                v = silu_f(BNCF * (v + bias[col]));
                v = BNCF * v;
            } else {
                v = BNCF * (v + bias[col]);
                v = silu_f(v + res[(long)row * 128 + col]);
            }
            if (OD == 0)
                ((u16*)Ov)[(long)row * Nn + col] = f2b(v);
            else
                ((float*)Ov)[(long)row * Nn + col] = v;
        }
    }
}

// ---------------------------------------------------------------- launcher
extern "C" void kernel_launch(void* const* d_in, const int* in_sizes, int n_in,
                              void* d_out, int out_size, void* d_ws, size_t ws_size,
                              hipStream_t stream) {
    const float* pos   = (const float*)d_in[0];
    const float* refl  = (const float*)d_in[1];
    const float* sfv   = (const float*)d_in[2];
    const int*   batch = (const int*)d_in[3];
    const int*   idxp  = (const int*)d_in[4];
    const int*   colp  = (const int*)d_in[5];
    // d_in[6] = row (derived as e>>4)
    const float* s_g  = (const float*)d_in[7];
    const float* s_b  = (const float*)d_in[8];
    const float* s_w1 = (const float*)d_in[9];
    const float* s_b1 = (const float*)d_in[10];
    const float* s_w2 = (const float*)d_in[11];
    const float* s_b2 = (const float*)d_in[12];
    const float* lkw  = (const float*)d_in[13];
    const float* lkb  = (const float*)d_in[14];
    const float* lng  = (const float*)d_in[15];
    const float* lnb  = (const float*)d_in[16];
    const float* l_w1 = (const float*)d_in[17];
    const float* l_b1 = (const float*)d_in[18];
    const float* l_w2 = (const float*)d_in[19];
    const float* l_b2 = (const float*)d_in[20];
    const float* expw = (const float*)d_in[21];
    const float* expb = (const float*)d_in[22];
    const float* dw1w = (const float*)d_in[23];
    const float* dw1b = (const float*)d_in[24];
    const float* pw1w = (const float*)d_in[25];
    const float* pw1b = (const float*)d_in[26];
    const float* dw2w = (const float*)d_in[27];
    const float* dw2b = (const float*)d_in[28];
    const float* pw2w = (const float*)d_in[29];
    const float* pw2b = (const float*)d_in[30];
    const float* prjw = (const float*)d_in[31];
    const float* prjb = (const float*)d_in[32];

    char* ws = (char*)d_ws;
    float* cent  = (float*)(ws + 0);                  // 64 B
    float* sfeat = (float*)(ws + 64);                 // M*3*4
    float* agg   = (float*)(ws + 393280);             // M*128*4
    u16*   u1    = (u16*)(ws + 17170496);             // M*512*2
    u16*   u2    = (u16*)(ws + 50724928);             // M*512*2
    u16*   xf    = (u16*)(ws + 50724928);             // N*32*2 (aliases u2; dead before u2 written)

    hipMemsetAsync(cent, 0, 64, stream);
    k_centers<<<512, 256, 0, stream>>>(pos, sfv, batch, cent);
    k_stem<<<1024, 128, 0, stream>>>(pos, refl, sfv, batch, cent, s_g, s_b,
                                     s_w1, s_b1, s_w2, s_b2, xf);
    k_sfeat<<<128, 256, 0, stream>>>(pos, idxp, colp, lkw, lkb, lng, lnb, sfeat);
    k_edge<<<4096, 256, 0, stream>>>(pos, refl, idxp, colp, xf, sfeat,
                                     l_w1, l_b1, l_w2, l_b2, agg);

    dim3 blk(256);
    k_gemm<0, 0, 0><<<dim3(8, 256), blk, 0, stream>>>(agg, expw, expb, dw1w, dw1b,
                                                      nullptr, u1, 128, 512);
    k_gemm<1, 1, 0><<<dim3(8, 256), blk, 0, stream>>>(u1, pw1w, pw1b, dw2w, dw2b,
                                                      nullptr, u2, 512, 512);
    k_gemm<1, 2, 0><<<dim3(8, 256), blk, 0, stream>>>(u2, pw2w, pw2b, nullptr, nullptr,
                                                      nullptr, u1, 512, 512);
    k_gemm<1, 3, 1><<<dim3(2, 256), blk, 0, stream>>>(u1, prjw, prjb, nullptr, nullptr,
                                                      agg, d_out, 512, 128);
}

// Round 4
// 749.535 us; speedup vs baseline: 1.5061x; 1.5061x over previous
//
#include <hip/hip_runtime.h>

typedef unsigned short u16;
typedef unsigned int   u32;
typedef __attribute__((ext_vector_type(8))) u16  u16x8;
typedef __attribute__((ext_vector_type(4))) float f32x4;

#define N_PTS   131072
#define M_PTS   32768
#define BNCF    0.9999950000374997f

__device__ __forceinline__ float b2f(u16 u) {
    u32 x = ((u32)u) << 16;
    float f;
    __builtin_memcpy(&f, &x, 4);
    return f;
}
__device__ __forceinline__ u16 f2b(float f) {
    u32 x;
    __builtin_memcpy(&x, &f, 4);
    u32 r = x + 0x7fffu + ((x >> 16) & 1u);
    return (u16)(r >> 16);
}
__device__ __forceinline__ float silu_f(float x) {
    return x / (1.0f + __expf(-x));
}

__device__ __forceinline__ f32x4 mfma_bf16(u16x8 a, u16x8 b, f32x4 c) {
    asm volatile("v_mfma_f32_16x16x32_bf16 %0, %1, %2, %0"
                 : "+v"(c) : "v"(a), "v"(b));
    return c;
}
// MAI->VALU wait-state guard: nops ordered between last MFMA and first VALU read of c.
__device__ __forceinline__ f32x4 acc_fence(f32x4 c) {
    asm volatile("s_nop 7\n\ts_nop 7\n\ts_nop 3" : "+v"(c));
    return c;
}

// ---------------------------------------------------------------- weight transpose f32[K][N] -> bf16 [N][K]
__global__ __launch_bounds__(256) void k_w2bt(const float* __restrict__ W,
                                              u16* __restrict__ Bt,
                                              int K, int Nn) {
    int idx = blockIdx.x * 256 + threadIdx.x;          // over (K/4)*Nn
    int tot = (K >> 2) * Nn;
    if (idx >= tot) return;
    int k4 = (idx / Nn) * 4;
    int n  = idx % Nn;
    ushort4 o;
    o.x = f2b(W[(long)(k4 + 0) * Nn + n]);
    o.y = f2b(W[(long)(k4 + 1) * Nn + n]);
    o.z = f2b(W[(long)(k4 + 2) * Nn + n]);
    o.w = f2b(W[(long)(k4 + 3) * Nn + n]);
    *(ushort4*)(&Bt[(long)n * K + k4]) = o;
}

// ---------------------------------------------------------------- centers
__global__ __launch_bounds__(256) void k_centers(const float* __restrict__ pos,
                                                 const float* __restrict__ sfv,
                                                 const int* __restrict__ batch,
                                                 float* __restrict__ acc) {
    __shared__ float ls[16];
    int t = threadIdx.x;
    if (t < 16) ls[t] = 0.0f;
    __syncthreads();
    int i = blockIdx.x * 256 + t;
    if (i < N_PTS) {
        int b = batch[i];
        float inv = 1.0f / sfv[b];
        atomicAdd(&ls[b * 4 + 0], pos[i * 3 + 0] * inv);
        atomicAdd(&ls[b * 4 + 1], pos[i * 3 + 1] * inv);
        atomicAdd(&ls[b * 4 + 2], pos[i * 3 + 2] * inv);
        atomicAdd(&ls[b * 4 + 3], 1.0f);
    }
    __syncthreads();
    if (t < 16) atomicAdd(&acc[t], ls[t]);
}

// ---------------------------------------------------------------- stem
__global__ __launch_bounds__(128) void k_stem(const float* __restrict__ pos,
                                              const float* __restrict__ refl,
                                              const float* __restrict__ sfv,
                                              const int* __restrict__ batch,
                                              const float* __restrict__ cacc,
                                              const float* __restrict__ g,
                                              const float* __restrict__ bb,
                                              const float* __restrict__ w1,
                                              const float* __restrict__ b1,
                                              const float* __restrict__ w2,
                                              const float* __restrict__ b2,
                                              u16* __restrict__ xout) {
    __shared__ float xin[128 * 98];
    const float FREQS[16] = {
        1.0f, 0.31622776601683794f, 0.1f, 0.031622776601683791f,
        0.01f, 0.0031622776601683794f, 0.001f, 0.00031622776601683794f,
        0.0001f, 3.1622776601683795e-05f, 1e-05f, 3.1622776601683796e-06f,
        1e-06f, 3.1622776601683797e-07f, 1e-07f, 3.1622776601683792e-08f};
    int t = threadIdx.x;
    int i = blockIdx.x * 128 + t;
    float* xr = &xin[t * 98];

    int b = batch[i];
    float s = 1.0f / sfv[b];
    float cnt = fmaxf(cacc[b * 4 + 3], 1.0f);
    float npv[3];
#pragma unroll
    for (int d = 0; d < 3; ++d)
        npv[d] = pos[i * 3 + d] * s - cacc[b * 4 + d] / cnt;

#pragma unroll
    for (int d = 0; d < 3; ++d) {
#pragma unroll
        for (int f = 0; f < 16; ++f) {
            float a = npv[d] * FREQS[f];
            float sv, cv;
            __sincosf(a, &sv, &cv);
            xr[d * 32 + f] = sv;
            xr[d * 32 + 16 + f] = cv;
        }
    }
    xr[96] = refl[i];

    float sum = 0.0f, sq = 0.0f;
    for (int k = 0; k < 97; ++k) {
        float v = xr[k];
        sum += v;
        sq += v * v;
    }
    float m = sum * (1.0f / 97.0f);
    float var = sq * (1.0f / 97.0f) - m * m;
    float rstd = rsqrtf(fmaxf(var, 0.0f) + 1e-5f);
    for (int k = 0; k < 97; ++k)
        xr[k] = (xr[k] - m) * rstd * g[k] + bb[k];

    float acc[32];
#pragma unroll
    for (int o = 0; o < 32; ++o) acc[o] = 0.0f;

    for (int j0 = 0; j0 < 64; j0 += 4) {
        float h0 = b1[j0 + 0], h1 = b1[j0 + 1];
        float h2 = b1[j0 + 2], h3 = b1[j0 + 3];
        for (int k = 0; k < 97; ++k) {
            float v = xr[k];
            const float* wp = w1 + k * 64 + j0;
            h0 += v * wp[0];
            h1 += v * wp[1];
            h2 += v * wp[2];
            h3 += v * wp[3];
        }
        float hh[4] = {h0, h1, h2, h3};
#pragma unroll
        for (int jj = 0; jj < 4; ++jj) {
            float hs = silu_f(BNCF * hh[jj]);
            const float* w2p = w2 + (j0 + jj) * 32;
#pragma unroll
            for (int o = 0; o < 32; ++o) acc[o] += hs * w2p[o];
        }
    }
    u16* xo = xout + (long)i * 32;
#pragma unroll
    for (int o = 0; o < 32; ++o)
        xo[o] = f2b(silu_f(BNCF * (acc[o] + b2[o])));
}

// ---------------------------------------------------------------- sfeat
__global__ __launch_bounds__(256) void k_sfeat(const float* __restrict__ pos,
                                               const int* __restrict__ idxp,
                                               const int* __restrict__ colp,
                                               const float* __restrict__ lkw,
                                               const float* __restrict__ lkb,
                                               const float* __restrict__ lng,
                                               const float* __restrict__ lnb,
                                               float* __restrict__ sfeat) {
    int r = blockIdx.x * 256 + threadIdx.x;
    if (r >= M_PTS) return;
    int ci = idxp[r];
    float cx = pos[ci * 3 + 0];
    float cy = pos[ci * 3 + 1];
    float cz = pos[ci * 3 + 2];
    float dsx = 0.0f, dsy = 0.0f, dsz = 0.0f;
    for (int e = 0; e < 16; ++e) {
        int c = colp[r * 16 + e];
        float dx = pos[c * 3 + 0] - cx;
        float dy = pos[c * 3 + 1] - cy;
        float dz = pos[c * 3 + 2] - cz;
        float nrm = sqrtf(dx * dx + dy * dy + dz * dz);
        float inv = 1.0f / (nrm + 1e-8f);
        dsx += dx * inv;
        dsy += dy * inv;
        dsz += dz * inv;
    }
    const float S3 = 0.57735026918962576f;
    const float sx[8] = {1, -1, 1, 1, -1, -1, 1, -1};
    const float sy[8] = {1, 1, -1, 1, -1, 1, -1, -1};
    const float sz[8] = {1, 1, 1, -1, 1, -1, -1, -1};
    float sc[3] = {lkb[0], lkb[1], lkb[2]};
#pragma unroll
    for (int j = 0; j < 8; ++j) {
        float nb = (sx[j] * dsx + sy[j] * dsy + sz[j] * dsz) * (S3 * (1.0f / 16.0f));
        sc[0] += nb * lkw[j * 3 + 0];
        sc[1] += nb * lkw[j * 3 + 1];
        sc[2] += nb * lkw[j * 3 + 2];
    }
    float m = (sc[0] + sc[1] + sc[2]) * (1.0f / 3.0f);
    float v = ((sc[0] - m) * (sc[0] - m) + (sc[1] - m) * (sc[1] - m) +
               (sc[2] - m) * (sc[2] - m)) * (1.0f / 3.0f);
    float rstd = rsqrtf(fmaxf(v, 0.0f) + 1e-5f);
#pragma unroll
    for (int c = 0; c < 3; ++c)
        sfeat[r * 3 + c] = (sc[c] - m) * rstd * lng[c] + lnb[c];
}

// ---------------------------------------------------------------- edge MLP + segment max
__global__ __launch_bounds__(256) void k_edge(const float* __restrict__ pos,
                                              const float* __restrict__ refl,
                                              const int* __restrict__ idxp,
                                              const int* __restrict__ colp,
                                              const u16* __restrict__ xfeat,
                                              const float* __restrict__ sfeat,
                                              const float* __restrict__ w1,
                                              const float* __restrict__ b1,
                                              const float* __restrict__ w2,
                                              const float* __restrict__ b2,
                                              float* __restrict__ agg,
                                              u16* __restrict__ aggb) {
    __shared__ float uni[8192];       // msg [128][41] then w2 [64*128]
    __shared__ u16 hbuf[128 * 65];    // bf16 hidden
    __shared__ float w1s[39 * 64];
    __shared__ float b1s[64];
    __shared__ float b2s[128];
    int t = threadIdx.x;
    int r0 = blockIdx.x * 8;
    long e0 = (long)r0 * 16;

    for (int u = t; u < 39 * 64; u += 256) w1s[u] = w1[u];
    if (t < 64) b1s[t] = b1[t];
    if (t < 128) b2s[t] = b2[t];

    for (int u = t; u < 128 * 4; u += 256) {
        int e = u >> 2, seg = u & 3;
        int c = colp[e0 + e];
        uint4 d = *(const uint4*)(xfeat + (long)c * 32 + seg * 8);
        float* mp = &uni[e * 41 + seg * 8];
        u32 ws_[4] = {d.x, d.y, d.z, d.w};
#pragma unroll
        for (int q = 0; q < 4; ++q) {
            mp[q * 2 + 0] = b2f((u16)(ws_[q] & 0xffffu));
            mp[q * 2 + 1] = b2f((u16)(ws_[q] >> 16));
        }
    }
    if (t < 128) {
        int e = t;
        int r = r0 + (e >> 4);
        int c = colp[e0 + e];
        int ci = idxp[r];
        float* mp = &uni[e * 41];
        mp[32] = pos[c * 3 + 0] - pos[ci * 3 + 0];
        mp[33] = pos[c * 3 + 1] - pos[ci * 3 + 1];
        mp[34] = pos[c * 3 + 2] - pos[ci * 3 + 2];
        mp[35] = refl[c] - refl[ci];
        mp[36] = sfeat[r * 3 + 0];
        mp[37] = sfeat[r * 3 + 1];
        mp[38] = sfeat[r * 3 + 2];
    }
    __syncthreads();

    {
        int q = t & 31;
        int j0 = (t >> 5) * 8;
        float acc[4][8];
#pragma unroll
        for (int i = 0; i < 4; ++i)
#pragma unroll
            for (int jj = 0; jj < 8; ++jj) acc[i][jj] = b1s[j0 + jj];
        for (int k = 0; k < 39; ++k) {
            float a0 = uni[(q + 0) * 41 + k];
            float a1 = uni[(q + 32) * 41 + k];
            float a2 = uni[(q + 64) * 41 + k];
            float a3 = uni[(q + 96) * 41 + k];
#pragma unroll
            for (int jj = 0; jj < 8; ++jj) {
                float w = w1s[k * 64 + j0 + jj];
                acc[0][jj] += a0 * w;
                acc[1][jj] += a1 * w;
                acc[2][jj] += a2 * w;
                acc[3][jj] += a3 * w;
            }
        }
#pragma unroll
        for (int i = 0; i < 4; ++i)
#pragma unroll
            for (int jj = 0; jj < 8; ++jj)
                hbuf[(q + 32 * i) * 65 + j0 + jj] =
                    f2b(silu_f(BNCF * acc[i][jj]));
    }
    __syncthreads();

    for (int u = t; u < 64 * 128; u += 256) uni[u] = w2[u];
    __syncthreads();

    {
        int rl = t >> 5;
        int o0 = t & 31;
        float acc[16][4];
#pragma unroll
        for (int e = 0; e < 16; ++e)
#pragma unroll
            for (int j = 0; j < 4; ++j) acc[e][j] = b2s[o0 + 32 * j];
        for (int k = 0; k < 64; ++k) {
            float wv[4];
#pragma unroll
            for (int j = 0; j < 4; ++j) wv[j] = uni[k * 128 + o0 + 32 * j];
#pragma unroll
            for (int e = 0; e < 16; ++e) {
                float hv = b2f(hbuf[(rl * 16 + e) * 65 + k]);
                acc[e][0] += hv * wv[0];
                acc[e][1] += hv * wv[1];
                acc[e][2] += hv * wv[2];
                acc[e][3] += hv * wv[3];
            }
        }
        int rg = r0 + rl;
#pragma unroll
        for (int j = 0; j < 4; ++j) {
            float mx = -1e30f;
#pragma unroll
            for (int e = 0; e < 16; ++e) {
                float v = silu_f(BNCF * acc[e][j]);
                mx = fmaxf(mx, v);
            }
            agg[(long)rg * 128 + o0 + 32 * j] = mx;
            aggb[(long)rg * 128 + o0 + 32 * j] = f2b(mx);
        }
    }
}

// ---------------------------------------------------------------- MFMA GEMM
// C[M][Nn] = A[M][K](bf16) @ W (Bt = W^T as bf16 [Nn][K]) + fused epilogue.
// 128x128 block tile, 4 waves 2x2, each wave 64x64 = 4x4 of 16x16x32 MFMA.
template <int EPI, int OD>
__global__ __launch_bounds__(256) void k_mgemm(const u16* __restrict__ A,
                                               const u16* __restrict__ Bt,
                                               const float* __restrict__ bias,
                                               const float* __restrict__ dww,
                                               const float* __restrict__ dwb,
                                               const float* __restrict__ res,
                                               void* __restrict__ Ov,
                                               int K, int Nn) {
    __shared__ u16 As[128][72];   // +8 pad: 2-way bank aliasing (free)
    __shared__ u16 Bs[128][72];
    int t = threadIdx.x;
    int wave = t >> 6, lane = t & 63;
    int quad = lane >> 4, l16 = lane & 15;
    int R0 = blockIdx.y * 128, C0 = blockIdx.x * 128;
    int wm = (wave & 1) * 64, wn = (wave >> 1) * 64;

    f32x4 acc[4][4];
#pragma unroll
    for (int i = 0; i < 4; ++i)
#pragma unroll
        for (int j = 0; j < 4; ++j) acc[i][j] = (f32x4){0.f, 0.f, 0.f, 0.f};

    for (int k0 = 0; k0 < K; k0 += 64) {
#pragma unroll
        for (int u = t; u < 1024; u += 256) {
            int row = u >> 3, c8 = (u & 7) * 8;
            uint4 v = *(const uint4*)(A + (long)(R0 + row) * K + k0 + c8);
            *(uint4*)(&As[row][c8]) = v;
        }
#pragma unroll
        for (int u = t; u < 1024; u += 256) {
            int row = u >> 3, c8 = (u & 7) * 8;
            uint4 v = *(const uint4*)(Bt + (long)(C0 + row) * K + k0 + c8);
            *(uint4*)(&Bs[row][c8]) = v;
        }
        __syncthreads();
#pragma unroll
        for (int kk = 0; kk < 64; kk += 32) {
            u16x8 af[4], bfr[4];
#pragma unroll
            for (int tm = 0; tm < 4; ++tm)
                af[tm] = *(const u16x8*)(&As[wm + tm * 16 + l16][kk + quad * 8]);
#pragma unroll
            for (int tn = 0; tn < 4; ++tn)
                bfr[tn] = *(const u16x8*)(&Bs[wn + tn * 16 + l16][kk + quad * 8]);
#pragma unroll
            for (int tm = 0; tm < 4; ++tm)
#pragma unroll
                for (int tn = 0; tn < 4; ++tn)
                    acc[tm][tn] = mfma_bf16(af[tm], bfr[tn], acc[tm][tn]);
        }
        __syncthreads();
    }

#pragma unroll
    for (int tm = 0; tm < 4; ++tm) {
#pragma unroll
        for (int tn = 0; tn < 4; ++tn) {
            f32x4 c = acc_fence(acc[tm][tn]);
            int n = C0 + wn + tn * 16 + l16;
#pragma unroll
            for (int r = 0; r < 4; ++r) {
                int m = R0 + wm + tm * 16 + quad * 4 + r;
                float v = c[r];
                if (EPI == 0) {
                    v = silu_f(BNCF * (v + bias[n]));
                    v = silu_f(BNCF * (v * dww[n] + dwb[n]));
                } else if (EPI == 1) {
                    v = silu_f(BNCF * (v + bias[n]));
                    v = silu_f(BNCF * v);
                    v = silu_f(BNCF * (v * dww[n] + dwb[n]));
                } else if (EPI == 2) {
                    v = silu_f(BNCF * (v + bias[n]));
                    v = BNCF * v;
                } else {
                    v = BNCF * (v + bias[n]);
                    v = silu_f(v + res[(long)m * 128 + n]);
                }
                if (OD == 0)
                    ((u16*)Ov)[(long)m * Nn + n] = f2b(v);
                else
                    ((float*)Ov)[(long)m * Nn + n] = v;
            }
        }
    }
}

// ---------------------------------------------------------------- launcher
extern "C" void kernel_launch(void* const* d_in, const int* in_sizes, int n_in,
                              void* d_out, int out_size, void* d_ws, size_t ws_size,
                              hipStream_t stream) {
    const float* pos   = (const float*)d_in[0];
    const float* refl  = (const float*)d_in[1];
    const float* sfv   = (const float*)d_in[2];
    const int*   batch = (const int*)d_in[3];
    const int*   idxp  = (const int*)d_in[4];
    const int*   colp  = (const int*)d_in[5];
    const float* s_g  = (const float*)d_in[7];
    const float* s_b  = (const float*)d_in[8];
    const float* s_w1 = (const float*)d_in[9];
    const float* s_b1 = (const float*)d_in[10];
    const float* s_w2 = (const float*)d_in[11];
    const float* s_b2 = (const float*)d_in[12];
    const float* lkw  = (const float*)d_in[13];
    const float* lkb  = (const float*)d_in[14];
    const float* lng  = (const float*)d_in[15];
    const float* lnb  = (const float*)d_in[16];
    const float* l_w1 = (const float*)d_in[17];
    const float* l_b1 = (const float*)d_in[18];
    const float* l_w2 = (const float*)d_in[19];
    const float* l_b2 = (const float*)d_in[20];
    const float* expw = (const float*)d_in[21];
    const float* expb = (const float*)d_in[22];
    const float* dw1w = (const float*)d_in[23];
    const float* dw1b = (const float*)d_in[24];
    const float* pw1w = (const float*)d_in[25];
    const float* pw1b = (const float*)d_in[26];
    const float* dw2w = (const float*)d_in[27];
    const float* dw2b = (const float*)d_in[28];
    const float* pw2w = (const float*)d_in[29];
    const float* pw2b = (const float*)d_in[30];
    const float* prjw = (const float*)d_in[31];
    const float* prjb = (const float*)d_in[32];

    char* ws = (char*)d_ws;
    float* cent  = (float*)(ws + 0);                  // 64 B
    float* sfeat = (float*)(ws + 64);                 // M*3*4
    float* agg   = (float*)(ws + 393280);             // M*128*4 f32
    u16*   aggb  = (u16*)(ws + 17170496);             // M*128*2 bf16
    u16*   u1    = (u16*)(ws + 25559104);             // M*512*2
    u16*   u2    = (u16*)(ws + 59113536);             // M*512*2
    u16*   xf    = (u16*)(ws + 59113536);             // N*32*2 (aliases u2; dead before u2 written)
    u16*   expwt = (u16*)(ws + 92667968);             // 512*128*2
    u16*   pw1t  = (u16*)(ws + 92799040);             // 512*512*2
    u16*   pw2t  = (u16*)(ws + 93323328);             // 512*512*2
    u16*   prjt  = (u16*)(ws + 93847616);             // 128*512*2

    // weight transposes (bf16)
    k_w2bt<<<(32 * 512 + 255) / 256, 256, 0, stream>>>(expw, expwt, 128, 512);
    k_w2bt<<<(128 * 512 + 255) / 256, 256, 0, stream>>>(pw1w, pw1t, 512, 512);
    k_w2bt<<<(128 * 512 + 255) / 256, 256, 0, stream>>>(pw2w, pw2t, 512, 512);
    k_w2bt<<<(128 * 128 + 255) / 256, 256, 0, stream>>>(prjw, prjt, 512, 128);

    hipMemsetAsync(cent, 0, 64, stream);
    k_centers<<<512, 256, 0, stream>>>(pos, sfv, batch, cent);
    k_stem<<<1024, 128, 0, stream>>>(pos, refl, sfv, batch, cent, s_g, s_b,
                                     s_w1, s_b1, s_w2, s_b2, xf);
    k_sfeat<<<128, 256, 0, stream>>>(pos, idxp, colp, lkw, lkb, lng, lnb, sfeat);
    k_edge<<<4096, 256, 0, stream>>>(pos, refl, idxp, colp, xf, sfeat,
                                     l_w1, l_b1, l_w2, l_b2, agg, aggb);

    dim3 blk(256);
    k_mgemm<0, 0><<<dim3(4, 256), blk, 0, stream>>>(aggb, expwt, expb, dw1w, dw1b,
                                                    nullptr, u1, 128, 512);
    k_mgemm<1, 0><<<dim3(4, 256), blk, 0, stream>>>(u1, pw1t, pw1b, dw2w, dw2b,
                                                    nullptr, u2, 512, 512);
    k_mgemm<2, 0><<<dim3(4, 256), blk, 0, stream>>>(u2, pw2t, pw2b, nullptr, nullptr,
                                                    nullptr, u1, 512, 512);
    k_mgemm<3, 1><<<dim3(1, 256), blk, 0, stream>>>(u1, prjt, prjb, nullptr, nullptr,
                                                    agg, d_out, 512, 128);
}

// Round 5
// 501.231 us; speedup vs baseline: 2.2522x; 1.4954x over previous
//
#include <hip/hip_runtime.h>

typedef unsigned short u16;
typedef unsigned int   u32;
typedef __attribute__((ext_vector_type(8))) u16  u16x8;
typedef __attribute__((ext_vector_type(4))) float f32x4;

#define N_PTS   131072
#define M_PTS   32768
#define BNCF    0.9999950000374997f

__device__ __forceinline__ float b2f(u16 u) {
    u32 x = ((u32)u) << 16;
    float f;
    __builtin_memcpy(&f, &x, 4);
    return f;
}
__device__ __forceinline__ u16 f2b(float f) {
    u32 x;
    __builtin_memcpy(&x, &f, 4);
    u32 r = x + 0x7fffu + ((x >> 16) & 1u);
    return (u16)(r >> 16);
}
__device__ __forceinline__ float silu_f(float x) {
    return x / (1.0f + __expf(-x));
}

__device__ __forceinline__ f32x4 mfma_bf16(u16x8 a, u16x8 b, f32x4 c) {
    asm volatile("v_mfma_f32_16x16x32_bf16 %0, %1, %2, %0"
                 : "+v"(c) : "v"(a), "v"(b));
    return c;
}
// MAI->VALU wait-state guard.
__device__ __forceinline__ f32x4 acc_fence(f32x4 c) {
    asm volatile("s_nop 7\n\ts_nop 7\n\ts_nop 3" : "+v"(c));
    return c;
}

// ---------------------------------------------------------------- weight transpose f32[K][N] -> bf16 [N][K]
__global__ __launch_bounds__(256) void k_w2bt(const float* __restrict__ W,
                                              u16* __restrict__ Bt,
                                              int K, int Nn) {
    int idx = blockIdx.x * 256 + threadIdx.x;
    int tot = (K >> 2) * Nn;
    if (idx >= tot) return;
    int k4 = (idx / Nn) * 4;
    int n  = idx % Nn;
    ushort4 o;
    o.x = f2b(W[(long)(k4 + 0) * Nn + n]);
    o.y = f2b(W[(long)(k4 + 1) * Nn + n]);
    o.z = f2b(W[(long)(k4 + 2) * Nn + n]);
    o.w = f2b(W[(long)(k4 + 3) * Nn + n]);
    *(ushort4*)(&Bt[(long)n * K + k4]) = o;
}

// f32[K][N] -> bf16 [N][Kpad], zero-padded K..Kpad
__global__ __launch_bounds__(256) void k_wt_pad(const float* __restrict__ W,
                                                u16* __restrict__ out,
                                                int K, int Kpad, int Nn) {
    int idx = blockIdx.x * 256 + threadIdx.x;
    if (idx >= Nn * Kpad) return;
    int n = idx / Kpad, k = idx % Kpad;
    out[idx] = (k < K) ? f2b(W[(long)k * Nn + n]) : (u16)0;
}

// ---------------------------------------------------------------- centers
__global__ __launch_bounds__(256) void k_centers(const float* __restrict__ pos,
                                                 const float* __restrict__ sfv,
                                                 const int* __restrict__ batch,
                                                 float* __restrict__ acc) {
    __shared__ float ls[16];
    int t = threadIdx.x;
    if (t < 16) ls[t] = 0.0f;
    __syncthreads();
    int i = blockIdx.x * 256 + t;
    if (i < N_PTS) {
        int b = batch[i];
        float inv = 1.0f / sfv[b];
        atomicAdd(&ls[b * 4 + 0], pos[i * 3 + 0] * inv);
        atomicAdd(&ls[b * 4 + 1], pos[i * 3 + 1] * inv);
        atomicAdd(&ls[b * 4 + 2], pos[i * 3 + 2] * inv);
        atomicAdd(&ls[b * 4 + 3], 1.0f);
    }
    __syncthreads();
    if (t < 16) atomicAdd(&acc[t], ls[t]);
}

// ---------------------------------------------------------------- stem
__global__ __launch_bounds__(128) void k_stem(const float* __restrict__ pos,
                                              const float* __restrict__ refl,
                                              const float* __restrict__ sfv,
                                              const int* __restrict__ batch,
                                              const float* __restrict__ cacc,
                                              const float* __restrict__ g,
                                              const float* __restrict__ bb,
                                              const float* __restrict__ w1,
                                              const float* __restrict__ b1,
                                              const float* __restrict__ w2,
                                              const float* __restrict__ b2,
                                              u16* __restrict__ xout) {
    __shared__ float xin[128 * 98];
    const float FREQS[16] = {
        1.0f, 0.31622776601683794f, 0.1f, 0.031622776601683791f,
        0.01f, 0.0031622776601683794f, 0.001f, 0.00031622776601683794f,
        0.0001f, 3.1622776601683795e-05f, 1e-05f, 3.1622776601683796e-06f,
        1e-06f, 3.1622776601683797e-07f, 1e-07f, 3.1622776601683792e-08f};
    int t = threadIdx.x;
    int i = blockIdx.x * 128 + t;
    float* xr = &xin[t * 98];

    int b = batch[i];
    float s = 1.0f / sfv[b];
    float cnt = fmaxf(cacc[b * 4 + 3], 1.0f);
    float npv[3];
#pragma unroll
    for (int d = 0; d < 3; ++d)
        npv[d] = pos[i * 3 + d] * s - cacc[b * 4 + d] / cnt;

#pragma unroll
    for (int d = 0; d < 3; ++d) {
#pragma unroll
        for (int f = 0; f < 16; ++f) {
            float a = npv[d] * FREQS[f];
            float sv, cv;
            __sincosf(a, &sv, &cv);
            xr[d * 32 + f] = sv;
            xr[d * 32 + 16 + f] = cv;
        }
    }
    xr[96] = refl[i];

    float sum = 0.0f, sq = 0.0f;
    for (int k = 0; k < 97; ++k) {
        float v = xr[k];
        sum += v;
        sq += v * v;
    }
    float m = sum * (1.0f / 97.0f);
    float var = sq * (1.0f / 97.0f) - m * m;
    float rstd = rsqrtf(fmaxf(var, 0.0f) + 1e-5f);
    for (int k = 0; k < 97; ++k)
        xr[k] = (xr[k] - m) * rstd * g[k] + bb[k];

    float acc[32];
#pragma unroll
    for (int o = 0; o < 32; ++o) acc[o] = 0.0f;

    for (int j0 = 0; j0 < 64; j0 += 4) {
        float h0 = b1[j0 + 0], h1 = b1[j0 + 1];
        float h2 = b1[j0 + 2], h3 = b1[j0 + 3];
        for (int k = 0; k < 97; ++k) {
            float v = xr[k];
            const float* wp = w1 + k * 64 + j0;
            h0 += v * wp[0];
            h1 += v * wp[1];
            h2 += v * wp[2];
            h3 += v * wp[3];
        }
        float hh[4] = {h0, h1, h2, h3};
#pragma unroll
        for (int jj = 0; jj < 4; ++jj) {
            float hs = silu_f(BNCF * hh[jj]);
            const float* w2p = w2 + (j0 + jj) * 32;
#pragma unroll
            for (int o = 0; o < 32; ++o) acc[o] += hs * w2p[o];
        }
    }
    u16* xo = xout + (long)i * 32;
#pragma unroll
    for (int o = 0; o < 32; ++o)
        xo[o] = f2b(silu_f(BNCF * (acc[o] + b2[o])));
}

// ---------------------------------------------------------------- sfeat
__global__ __launch_bounds__(256) void k_sfeat(const float* __restrict__ pos,
                                               const int* __restrict__ idxp,
                                               const int* __restrict__ colp,
                                               const float* __restrict__ lkw,
                                               const float* __restrict__ lkb,
                                               const float* __restrict__ lng,
                                               const float* __restrict__ lnb,
                                               float* __restrict__ sfeat) {
    int r = blockIdx.x * 256 + threadIdx.x;
    if (r >= M_PTS) return;
    int ci = idxp[r];
    float cx = pos[ci * 3 + 0];
    float cy = pos[ci * 3 + 1];
    float cz = pos[ci * 3 + 2];
    float dsx = 0.0f, dsy = 0.0f, dsz = 0.0f;
    for (int e = 0; e < 16; ++e) {
        int c = colp[r * 16 + e];
        float dx = pos[c * 3 + 0] - cx;
        float dy = pos[c * 3 + 1] - cy;
        float dz = pos[c * 3 + 2] - cz;
        float nrm = sqrtf(dx * dx + dy * dy + dz * dz);
        float inv = 1.0f / (nrm + 1e-8f);
        dsx += dx * inv;
        dsy += dy * inv;
        dsz += dz * inv;
    }
    const float S3 = 0.57735026918962576f;
    const float sx[8] = {1, -1, 1, 1, -1, -1, 1, -1};
    const float sy[8] = {1, 1, -1, 1, -1, 1, -1, -1};
    const float sz[8] = {1, 1, 1, -1, 1, -1, -1, -1};
    float sc[3] = {lkb[0], lkb[1], lkb[2]};
#pragma unroll
    for (int j = 0; j < 8; ++j) {
        float nb = (sx[j] * dsx + sy[j] * dsy + sz[j] * dsz) * (S3 * (1.0f / 16.0f));
        sc[0] += nb * lkw[j * 3 + 0];
        sc[1] += nb * lkw[j * 3 + 1];
        sc[2] += nb * lkw[j * 3 + 2];
    }
    float m = (sc[0] + sc[1] + sc[2]) * (1.0f / 3.0f);
    float v = ((sc[0] - m) * (sc[0] - m) + (sc[1] - m) * (sc[1] - m) +
               (sc[2] - m) * (sc[2] - m)) * (1.0f / 3.0f);
    float rstd = rsqrtf(fmaxf(v, 0.0f) + 1e-5f);
#pragma unroll
    for (int c = 0; c < 3; ++c)
        sfeat[r * 3 + c] = (sc[c] - m) * rstd * lng[c] + lnb[c];
}

// ---------------------------------------------------------------- edge MLP + segment max (MFMA)
// 8 graph rows = 128 edges per block. Phase1: msg(64pad)@w1t -> h(64).
// Phase2: h @ w2t -> 128 out, fused silu + segment-max (16 edges = one m-tile).
__global__ __launch_bounds__(256) void k_edge(const float* __restrict__ pos,
                                              const float* __restrict__ refl,
                                              const int* __restrict__ idxp,
                                              const int* __restrict__ colp,
                                              const u16* __restrict__ xfeat,
                                              const float* __restrict__ sfeat,
                                              const u16* __restrict__ w1t,
                                              const float* __restrict__ b1,
                                              const u16* __restrict__ w2t,
                                              const float* __restrict__ b2,
                                              float* __restrict__ agg,
                                              u16* __restrict__ aggb) {
    __shared__ u16 uni16[128 * 72];   // msg bf16 [128][72] (K 0..63, pad 64..71), then w2t [128][72]
    __shared__ u16 hs[128 * 72];      // h bf16 [128][72]
    __shared__ u16 w1s[64 * 72];      // w1t bf16 [64][72]
    __shared__ float b1s[64];
    __shared__ float b2s[128];
    int t = threadIdx.x;
    int r0 = blockIdx.x * 8;
    long e0 = (long)r0 * 16;
    int wave = t >> 6, lane = t & 63;
    int quad = lane >> 4, l16 = lane & 15;
    int mt0 = wave * 2;               // 2 m-tiles per wave

    // stage w1t
    for (int u = t; u < 512; u += 256) {
        int row = u >> 3, c8 = (u & 7) * 8;
        *(uint4*)(&w1s[row * 72 + c8]) = *(const uint4*)(w1t + row * 64 + c8);
    }
    if (t < 64) b1s[t] = b1[t];
    if (t < 128) b2s[t] = b2[t];

    // stage x -> msg cols 0..31 (raw bf16)
    for (int u = t; u < 512; u += 256) {
        int e = u >> 2, seg = u & 3;
        int c = colp[e0 + e];
        uint4 d = *(const uint4*)(xfeat + (long)c * 32 + seg * 8);
        *(uint4*)(&uni16[e * 72 + seg * 8]) = d;
    }
    // rel + sfeat -> cols 32..38, zeros 39..63
    if (t < 128) {
        int e = t;
        int r = r0 + (e >> 4);
        int c = colp[e0 + e];
        int ci = idxp[r];
        u16 tmp[8];
        tmp[0] = f2b(pos[c * 3 + 0] - pos[ci * 3 + 0]);
        tmp[1] = f2b(pos[c * 3 + 1] - pos[ci * 3 + 1]);
        tmp[2] = f2b(pos[c * 3 + 2] - pos[ci * 3 + 2]);
        tmp[3] = f2b(refl[c] - refl[ci]);
        tmp[4] = f2b(sfeat[r * 3 + 0]);
        tmp[5] = f2b(sfeat[r * 3 + 1]);
        tmp[6] = f2b(sfeat[r * 3 + 2]);
        tmp[7] = 0;
        *(uint4*)(&uni16[e * 72 + 32]) = *(uint4*)tmp;
        uint4 z = {0, 0, 0, 0};
        *(uint4*)(&uni16[e * 72 + 40]) = z;
        *(uint4*)(&uni16[e * 72 + 48]) = z;
        *(uint4*)(&uni16[e * 72 + 56]) = z;
    }
    __syncthreads();

    // phase 1: msg @ w1t -> h   (per wave: 2 m-tiles x 4 n-tiles)
    {
        f32x4 acc[2][4];
#pragma unroll
        for (int i = 0; i < 2; ++i)
#pragma unroll
            for (int j = 0; j < 4; ++j) acc[i][j] = (f32x4){0.f, 0.f, 0.f, 0.f};
#pragma unroll
        for (int kk = 0; kk < 64; kk += 32) {
            u16x8 af[2], bfr[4];
#pragma unroll
            for (int i = 0; i < 2; ++i)
                af[i] = *(const u16x8*)(&uni16[((mt0 + i) * 16 + l16) * 72 + kk + quad * 8]);
#pragma unroll
            for (int j = 0; j < 4; ++j)
                bfr[j] = *(const u16x8*)(&w1s[(j * 16 + l16) * 72 + kk + quad * 8]);
#pragma unroll
            for (int i = 0; i < 2; ++i)
#pragma unroll
                for (int j = 0; j < 4; ++j)
                    acc[i][j] = mfma_bf16(af[i], bfr[j], acc[i][j]);
        }
#pragma unroll
        for (int i = 0; i < 2; ++i)
#pragma unroll
            for (int j = 0; j < 4; ++j) {
                f32x4 c = acc_fence(acc[i][j]);
                int n = j * 16 + l16;
#pragma unroll
                for (int r = 0; r < 4; ++r) {
                    float v = silu_f(BNCF * (c[r] + b1s[n]));
                    hs[((mt0 + i) * 16 + quad * 4 + r) * 72 + n] = f2b(v);
                }
            }
    }
    __syncthreads();   // all waves done reading msg

    // stage w2t into uni16
    for (int u = t; u < 1024; u += 256) {
        int row = u >> 3, c8 = (u & 7) * 8;
        *(uint4*)(&uni16[row * 72 + c8]) = *(const uint4*)(w2t + row * 64 + c8);
    }
    __syncthreads();

    // phase 2: h @ w2t -> out(128) + fused silu/segment-max
    {
        f32x4 acc[2][8];
#pragma unroll
        for (int i = 0; i < 2; ++i)
#pragma unroll
            for (int j = 0; j < 8; ++j) acc[i][j] = (f32x4){0.f, 0.f, 0.f, 0.f};
#pragma unroll
        for (int kk = 0; kk < 64; kk += 32) {
            u16x8 af[2], bfr[8];
#pragma unroll
            for (int i = 0; i < 2; ++i)
                af[i] = *(const u16x8*)(&hs[((mt0 + i) * 16 + l16) * 72 + kk + quad * 8]);
#pragma unroll
            for (int j = 0; j < 8; ++j)
                bfr[j] = *(const u16x8*)(&uni16[(j * 16 + l16) * 72 + kk + quad * 8]);
#pragma unroll
            for (int i = 0; i < 2; ++i)
#pragma unroll
                for (int j = 0; j < 8; ++j)
                    acc[i][j] = mfma_bf16(af[i], bfr[j], acc[i][j]);
        }
#pragma unroll
        for (int i = 0; i < 2; ++i) {
            int rg = r0 + mt0 + i;
#pragma unroll
            for (int j = 0; j < 8; ++j) {
                f32x4 c = acc_fence(acc[i][j]);
                int n = j * 16 + l16;
                float mx = -1e30f;
#pragma unroll
                for (int r = 0; r < 4; ++r)
                    mx = fmaxf(mx, silu_f(BNCF * (c[r] + b2s[n])));
                mx = fmaxf(mx, __shfl_xor(mx, 16));
                mx = fmaxf(mx, __shfl_xor(mx, 32));
                if (quad == 0) {
                    agg[(long)rg * 128 + n] = mx;
                    aggb[(long)rg * 128 + n] = f2b(mx);
                }
            }
        }
    }
}

// ---------------------------------------------------------------- MFMA GEMM
// 128x128 block tile, 4 waves 2x2, each wave 64x64 = 4x4 of 16x16x32 MFMA.
template <int EPI, int OD>
__global__ __launch_bounds__(256) void k_mgemm(const u16* __restrict__ A,
                                               const u16* __restrict__ Bt,
                                               const float* __restrict__ bias,
                                               const float* __restrict__ dww,
                                               const float* __restrict__ dwb,
                                               const float* __restrict__ res,
                                               void* __restrict__ Ov,
                                               int K, int Nn) {
    __shared__ u16 As[128][72];
    __shared__ u16 Bs[128][72];
    int t = threadIdx.x;
    int wave = t >> 6, lane = t & 63;
    int quad = lane >> 4, l16 = lane & 15;
    int R0 = blockIdx.y * 128, C0 = blockIdx.x * 128;
    int wm = (wave & 1) * 64, wn = (wave >> 1) * 64;

    f32x4 acc[4][4];
#pragma unroll
    for (int i = 0; i < 4; ++i)
#pragma unroll
        for (int j = 0; j < 4; ++j) acc[i][j] = (f32x4){0.f, 0.f, 0.f, 0.f};

    for (int k0 = 0; k0 < K; k0 += 64) {
#pragma unroll
        for (int u = t; u < 1024; u += 256) {
            int row = u >> 3, c8 = (u & 7) * 8;
            uint4 v = *(const uint4*)(A + (long)(R0 + row) * K + k0 + c8);
            *(uint4*)(&As[row][c8]) = v;
        }
#pragma unroll
        for (int u = t; u < 1024; u += 256) {
            int row = u >> 3, c8 = (u & 7) * 8;
            uint4 v = *(const uint4*)(Bt + (long)(C0 + row) * K + k0 + c8);
            *(uint4*)(&Bs[row][c8]) = v;
        }
        __syncthreads();
#pragma unroll
        for (int kk = 0; kk < 64; kk += 32) {
            u16x8 af[4], bfr[4];
#pragma unroll
            for (int tm = 0; tm < 4; ++tm)
                af[tm] = *(const u16x8*)(&As[wm + tm * 16 + l16][kk + quad * 8]);
#pragma unroll
            for (int tn = 0; tn < 4; ++tn)
                bfr[tn] = *(const u16x8*)(&Bs[wn + tn * 16 + l16][kk + quad * 8]);
#pragma unroll
            for (int tm = 0; tm < 4; ++tm)
#pragma unroll
                for (int tn = 0; tn < 4; ++tn)
                    acc[tm][tn] = mfma_bf16(af[tm], bfr[tn], acc[tm][tn]);
        }
        __syncthreads();
    }

#pragma unroll
    for (int tm = 0; tm < 4; ++tm) {
#pragma unroll
        for (int tn = 0; tn < 4; ++tn) {
            f32x4 c = acc_fence(acc[tm][tn]);
            int n = C0 + wn + tn * 16 + l16;
#pragma unroll
            for (int r = 0; r < 4; ++r) {
                int m = R0 + wm + tm * 16 + quad * 4 + r;
                float v = c[r];
                if (EPI == 0) {
                    v = silu_f(BNCF * (v + bias[n]));
                    v = silu_f(BNCF * (v * dww[n] + dwb[n]));
                } else if (EPI == 1) {
                    v = silu_f(BNCF * (v + bias[n]));
                    v = silu_f(BNCF * v);
                    v = silu_f(BNCF * (v * dww[n] + dwb[n]));
                } else if (EPI == 2) {
                    v = silu_f(BNCF * (v + bias[n]));
                    v = BNCF * v;
                } else {
                    v = BNCF * (v + bias[n]);
                    v = silu_f(v + res[(long)m * 128 + n]);
                }
                if (OD == 0)
                    ((u16*)Ov)[(long)m * Nn + n] = f2b(v);
                else
                    ((float*)Ov)[(long)m * Nn + n] = v;
            }
        }
    }
}

// ---------------------------------------------------------------- launcher
extern "C" void kernel_launch(void* const* d_in, const int* in_sizes, int n_in,
                              void* d_out, int out_size, void* d_ws, size_t ws_size,
                              hipStream_t stream) {
    const float* pos   = (const float*)d_in[0];
    const float* refl  = (const float*)d_in[1];
    const float* sfv   = (const float*)d_in[2];
    const int*   batch = (const int*)d_in[3];
    const int*   idxp  = (const int*)d_in[4];
    const int*   colp  = (const int*)d_in[5];
    const float* s_g  = (const float*)d_in[7];
    const float* s_b  = (const float*)d_in[8];
    const float* s_w1 = (const float*)d_in[9];
    const float* s_b1 = (const float*)d_in[10];
    const float* s_w2 = (const float*)d_in[11];
    const float* s_b2 = (const float*)d_in[12];
    const float* lkw  = (const float*)d_in[13];
    const float* lkb  = (const float*)d_in[14];
    const float* lng  = (const float*)d_in[15];
    const float* lnb  = (const float*)d_in[16];
    const float* l_w1 = (const float*)d_in[17];
    const float* l_b1 = (const float*)d_in[18];
    const float* l_w2 = (const float*)d_in[19];
    const float* l_b2 = (const float*)d_in[20];
    const float* expw = (const float*)d_in[21];
    const float* expb = (const float*)d_in[22];
    const float* dw1w = (const float*)d_in[23];
    const float* dw1b = (const float*)d_in[24];
    const float* pw1w = (const float*)d_in[25];
    const float* pw1b = (const float*)d_in[26];
    const float* dw2w = (const float*)d_in[27];
    const float* dw2b = (const float*)d_in[28];
    const float* pw2w = (const float*)d_in[29];
    const float* pw2b = (const float*)d_in[30];
    const float* prjw = (const float*)d_in[31];
    const float* prjb = (const float*)d_in[32];

    char* ws = (char*)d_ws;
    float* cent  = (float*)(ws + 0);                  // 64 B
    float* sfeat = (float*)(ws + 64);                 // M*3*4
    float* agg   = (float*)(ws + 393280);             // M*128*4 f32
    u16*   aggb  = (u16*)(ws + 17170496);             // M*128*2 bf16
    u16*   u1    = (u16*)(ws + 25559104);             // M*512*2
    u16*   u2    = (u16*)(ws + 59113536);             // M*512*2
    u16*   xf    = (u16*)(ws + 59113536);             // N*32*2 (aliases u2; dead before u2 written)
    u16*   expwt = (u16*)(ws + 92667968);             // 512*128*2
    u16*   pw1t  = (u16*)(ws + 92799040);             // 512*512*2
    u16*   pw2t  = (u16*)(ws + 93323328);             // 512*512*2
    u16*   prjt  = (u16*)(ws + 93847616);             // 128*512*2
    u16*   lw1t  = (u16*)(ws + 93978688);             // 64*64*2   = 8192
    u16*   lw2t  = (u16*)(ws + 93986880);             // 128*64*2  = 16384

    // weight transposes (bf16)
    k_w2bt<<<(32 * 512 + 255) / 256, 256, 0, stream>>>(expw, expwt, 128, 512);
    k_w2bt<<<(128 * 512 + 255) / 256, 256, 0, stream>>>(pw1w, pw1t, 512, 512);
    k_w2bt<<<(128 * 512 + 255) / 256, 256, 0, stream>>>(pw2w, pw2t, 512, 512);
    k_w2bt<<<(128 * 128 + 255) / 256, 256, 0, stream>>>(prjw, prjt, 512, 128);
    k_wt_pad<<<16, 256, 0, stream>>>(l_w1, lw1t, 39, 64, 64);
    k_wt_pad<<<32, 256, 0, stream>>>(l_w2, lw2t, 64, 64, 128);

    hipMemsetAsync(cent, 0, 64, stream);
    k_centers<<<512, 256, 0, stream>>>(pos, sfv, batch, cent);
    k_stem<<<1024, 128, 0, stream>>>(pos, refl, sfv, batch, cent, s_g, s_b,
                                     s_w1, s_b1, s_w2, s_b2, xf);
    k_sfeat<<<128, 256, 0, stream>>>(pos, idxp, colp, lkw, lkb, lng, lnb, sfeat);
    k_edge<<<4096, 256, 0, stream>>>(pos, refl, idxp, colp, xf, sfeat,
                                     lw1t, l_b1, lw2t, l_b2, agg, aggb);

    dim3 blk(256);
    k_mgemm<0, 0><<<dim3(4, 256), blk, 0, stream>>>(aggb, expwt, expb, dw1w, dw1b,
                                                    nullptr, u1, 128, 512);
    k_mgemm<1, 0><<<dim3(4, 256), blk, 0, stream>>>(u1, pw1t, pw1b, dw2w, dw2b,
                                                    nullptr, u2, 512, 512);
    k_mgemm<2, 0><<<dim3(4, 256), blk, 0, stream>>>(u2, pw2t, pw2b, nullptr, nullptr,
                                                    nullptr, u1, 512, 512);
    k_mgemm<3, 1><<<dim3(1, 256), blk, 0, stream>>>(u1, prjt, prjb, nullptr, nullptr,
                                                    agg, d_out, 512, 128);
}

// Round 6
// 432.747 us; speedup vs baseline: 2.6086x; 1.1583x over previous
//
#include <hip/hip_runtime.h>

typedef unsigned short u16;
typedef unsigned int   u32;
typedef __attribute__((ext_vector_type(8))) u16  u16x8;
typedef __attribute__((ext_vector_type(4))) float f32x4;

#define N_PTS   131072
#define M_PTS   32768
#define BNCF    0.9999950000374997f

__device__ __forceinline__ float b2f(u16 u) {
    u32 x = ((u32)u) << 16;
    float f;
    __builtin_memcpy(&f, &x, 4);
    return f;
}
__device__ __forceinline__ u16 f2b(float f) {
    u32 x;
    __builtin_memcpy(&x, &f, 4);
    u32 r = x + 0x7fffu + ((x >> 16) & 1u);
    return (u16)(r >> 16);
}
__device__ __forceinline__ float silu_f(float x) {
    return x / (1.0f + __expf(-x));
}

__device__ __forceinline__ f32x4 mfma_bf16(u16x8 a, u16x8 b, f32x4 c) {
    asm volatile("v_mfma_f32_16x16x32_bf16 %0, %1, %2, %0"
                 : "+v"(c) : "v"(a), "v"(b));
    return c;
}
// MAI->VALU wait-state guard.
__device__ __forceinline__ f32x4 acc_fence(f32x4 c) {
    asm volatile("s_nop 7\n\ts_nop 7\n\ts_nop 3" : "+v"(c));
    return c;
}

// ---------------------------------------------------------------- all weight transposes in ONE dispatch
// out[n*Kpad + k] = (k<K) ? bf16(W[k*N + n]) : 0
__global__ __launch_bounds__(256) void k_prep(const float* __restrict__ expw, u16* __restrict__ expwt,
                                              const float* __restrict__ pw1w, u16* __restrict__ pw1t,
                                              const float* __restrict__ pw2w, u16* __restrict__ pw2t,
                                              const float* __restrict__ prjw, u16* __restrict__ prjt,
                                              const float* __restrict__ lw1,  u16* __restrict__ lw1t,
                                              const float* __restrict__ lw2,  u16* __restrict__ lw2t,
                                              const float* __restrict__ sw1,  u16* __restrict__ sw1t,
                                              const float* __restrict__ sw2,  u16* __restrict__ sw2t) {
    int idx = blockIdx.x * 256 + threadIdx.x;
    const float* W; u16* O; int K, Kp, Nn;
    if (idx < 65536)                 { W = expw; O = expwt; K = 128; Kp = 128; Nn = 512; }
    else if ((idx -= 65536) < 262144){ W = pw1w; O = pw1t;  K = 512; Kp = 512; Nn = 512; }
    else if ((idx -= 262144) < 262144){ W = pw2w; O = pw2t; K = 512; Kp = 512; Nn = 512; }
    else if ((idx -= 262144) < 65536){ W = prjw; O = prjt;  K = 512; Kp = 512; Nn = 128; }
    else if ((idx -= 65536) < 4096)  { W = lw1;  O = lw1t;  K = 39;  Kp = 64;  Nn = 64;  }
    else if ((idx -= 4096) < 8192)   { W = lw2;  O = lw2t;  K = 64;  Kp = 64;  Nn = 128; }
    else if ((idx -= 8192) < 8192)   { W = sw1;  O = sw1t;  K = 97;  Kp = 128; Nn = 64;  }
    else if ((idx -= 8192) < 2048)   { W = sw2;  O = sw2t;  K = 64;  Kp = 64;  Nn = 32;  }
    else return;
    int n = idx / Kp, k = idx % Kp;
    O[idx] = (k < K) ? f2b(W[(long)k * Nn + n]) : (u16)0;
}

// ---------------------------------------------------------------- centers
__global__ __launch_bounds__(256) void k_centers(const float* __restrict__ pos,
                                                 const float* __restrict__ sfv,
                                                 const int* __restrict__ batch,
                                                 float* __restrict__ acc) {
    __shared__ float ls[16];
    int t = threadIdx.x;
    if (t < 16) ls[t] = 0.0f;
    __syncthreads();
    int i = blockIdx.x * 256 + t;
    if (i < N_PTS) {
        int b = batch[i];
        float inv = 1.0f / sfv[b];
        atomicAdd(&ls[b * 4 + 0], pos[i * 3 + 0] * inv);
        atomicAdd(&ls[b * 4 + 1], pos[i * 3 + 1] * inv);
        atomicAdd(&ls[b * 4 + 2], pos[i * 3 + 2] * inv);
        atomicAdd(&ls[b * 4 + 3], 1.0f);
    }
    __syncthreads();
    if (t < 16) atomicAdd(&acc[t], ls[t]);
}

// ---------------------------------------------------------------- stem (MFMA)
// 256 threads, 128 points/block. PE+LN -> bf16 xs[128][136] (K 97 -> padded 128),
// MFMA1 (K=128) -> silu -> hb[128][72], MFMA2 (K=64) -> silu -> x[128][32].
__global__ __launch_bounds__(256) void k_stem(const float* __restrict__ pos,
                                              const float* __restrict__ refl,
                                              const float* __restrict__ sfv,
                                              const int* __restrict__ batch,
                                              const float* __restrict__ cacc,
                                              const float* __restrict__ g,
                                              const float* __restrict__ bb,
                                              const u16* __restrict__ w1t,   // [64][128] bf16 (zero pad k>=97)
                                              const float* __restrict__ b1,
                                              const u16* __restrict__ w2t,   // [32][64] bf16
                                              const float* __restrict__ b2,
                                              u16* __restrict__ xout) {
    __shared__ u16 xs[128][136];
    __shared__ u16 hb[128][72];
    __shared__ u16 w1s[64][136];
    __shared__ u16 w2s[32][72];
    __shared__ float b1s[64];
    __shared__ float b2s[32];
    const float FREQS[16] = {
        1.0f, 0.31622776601683794f, 0.1f, 0.031622776601683791f,
        0.01f, 0.0031622776601683794f, 0.001f, 0.00031622776601683794f,
        0.0001f, 3.1622776601683795e-05f, 1e-05f, 3.1622776601683796e-06f,
        1e-06f, 3.1622776601683797e-07f, 1e-07f, 3.1622776601683792e-08f};
    int t = threadIdx.x;
    int wave = t >> 6, lane = t & 63;
    int quad = lane >> 4, l16 = lane & 15;
    int mt0 = wave * 2;

    // zero xs (covers K-pad region)
    for (int u = t; u < 1088; u += 256) ((uint4*)xs)[u] = (uint4){0, 0, 0, 0};
    // stage w1t, w2t, biases
    for (int u = t; u < 1024; u += 256) {
        int row = u >> 4, c8 = (u & 15) * 8;
        *(uint4*)(&w1s[row][c8]) = *(const uint4*)(w1t + row * 128 + c8);
    }
    {
        int row = t >> 3, c8 = (t & 7) * 8;
        *(uint4*)(&w2s[row][c8]) = *(const uint4*)(w2t + row * 64 + c8);
    }
    if (t < 64) b1s[t] = b1[t];
    if (t < 32) b2s[t] = b2[t];
    __syncthreads();

    // ---- PE + LN (threads 0..127, one point each)
    if (t < 128) {
        int i = blockIdx.x * 128 + t;
        int b = batch[i];
        float s = 1.0f / sfv[b];
        float cnt = fmaxf(cacc[b * 4 + 3], 1.0f);
        float npv[3];
#pragma unroll
        for (int d = 0; d < 3; ++d)
            npv[d] = pos[i * 3 + d] * s - cacc[b * 4 + d] / cnt;

        float sum = 0.0f, sq = 0.0f;
#pragma unroll
        for (int d = 0; d < 3; ++d) {
#pragma unroll
            for (int f = 0; f < 16; ++f) {
                float a = npv[d] * FREQS[f];
                float sv, cv;
                __sincosf(a, &sv, &cv);
                sum += sv + cv;
                sq += sv * sv + cv * cv;
                xs[t][d * 32 + f] = f2b(sv);
                xs[t][d * 32 + 16 + f] = f2b(cv);
            }
        }
        float rf = refl[i];
        sum += rf;
        sq += rf * rf;
        xs[t][96] = f2b(rf);

        float m = sum * (1.0f / 97.0f);
        float var = sq * (1.0f / 97.0f) - m * m;
        float rstd = rsqrtf(fmaxf(var, 0.0f) + 1e-5f);
        for (int k = 0; k < 97; ++k) {
            float v = b2f(xs[t][k]);
            xs[t][k] = f2b((v - m) * rstd * g[k] + bb[k]);
        }
    }
    __syncthreads();

    // ---- MFMA1: xs @ w1t -> hb (silu)
    {
        f32x4 acc[2][4];
#pragma unroll
        for (int i = 0; i < 2; ++i)
#pragma unroll
            for (int j = 0; j < 4; ++j) acc[i][j] = (f32x4){0.f, 0.f, 0.f, 0.f};
#pragma unroll
        for (int kk = 0; kk < 128; kk += 32) {
            u16x8 af[2], bfr[4];
#pragma unroll
            for (int i = 0; i < 2; ++i)
                af[i] = *(const u16x8*)(&xs[(mt0 + i) * 16 + l16][kk + quad * 8]);
#pragma unroll
            for (int j = 0; j < 4; ++j)
                bfr[j] = *(const u16x8*)(&w1s[j * 16 + l16][kk + quad * 8]);
#pragma unroll
            for (int i = 0; i < 2; ++i)
#pragma unroll
                for (int j = 0; j < 4; ++j)
                    acc[i][j] = mfma_bf16(af[i], bfr[j], acc[i][j]);
        }
#pragma unroll
        for (int i = 0; i < 2; ++i)
#pragma unroll
            for (int j = 0; j < 4; ++j) {
                f32x4 c = acc_fence(acc[i][j]);
                int n = j * 16 + l16;
#pragma unroll
                for (int r = 0; r < 4; ++r)
                    hb[(mt0 + i) * 16 + quad * 4 + r][n] =
                        f2b(silu_f(BNCF * (c[r] + b1s[n])));
            }
    }
    __syncthreads();

    // ---- MFMA2: hb @ w2t -> x (silu), write global
    {
        f32x4 acc[2][2];
#pragma unroll
        for (int i = 0; i < 2; ++i)
#pragma unroll
            for (int j = 0; j < 2; ++j) acc[i][j] = (f32x4){0.f, 0.f, 0.f, 0.f};
#pragma unroll
        for (int kk = 0; kk < 64; kk += 32) {
            u16x8 af[2], bfr[2];
#pragma unroll
            for (int i = 0; i < 2; ++i)
                af[i] = *(const u16x8*)(&hb[(mt0 + i) * 16 + l16][kk + quad * 8]);
#pragma unroll
            for (int j = 0; j < 2; ++j)
                bfr[j] = *(const u16x8*)(&w2s[j * 16 + l16][kk + quad * 8]);
#pragma unroll
            for (int i = 0; i < 2; ++i)
#pragma unroll
                for (int j = 0; j < 2; ++j)
                    acc[i][j] = mfma_bf16(af[i], bfr[j], acc[i][j]);
        }
#pragma unroll
        for (int i = 0; i < 2; ++i)
#pragma unroll
            for (int j = 0; j < 2; ++j) {
                f32x4 c = acc_fence(acc[i][j]);
                int n = j * 16 + l16;
#pragma unroll
                for (int r = 0; r < 4; ++r) {
                    int m = (mt0 + i) * 16 + quad * 4 + r;
                    long ig = (long)blockIdx.x * 128 + m;
                    xout[ig * 32 + n] = f2b(silu_f(BNCF * (c[r] + b2s[n])));
                }
            }
    }
}

// ---------------------------------------------------------------- sfeat
__global__ __launch_bounds__(256) void k_sfeat(const float* __restrict__ pos,
                                               const int* __restrict__ idxp,
                                               const int* __restrict__ colp,
                                               const float* __restrict__ lkw,
                                               const float* __restrict__ lkb,
                                               const float* __restrict__ lng,
                                               const float* __restrict__ lnb,
                                               float* __restrict__ sfeat) {
    int r = blockIdx.x * 256 + threadIdx.x;
    if (r >= M_PTS) return;
    int ci = idxp[r];
    float cx = pos[ci * 3 + 0];
    float cy = pos[ci * 3 + 1];
    float cz = pos[ci * 3 + 2];
    float dsx = 0.0f, dsy = 0.0f, dsz = 0.0f;
    for (int e = 0; e < 16; ++e) {
        int c = colp[r * 16 + e];
        float dx = pos[c * 3 + 0] - cx;
        float dy = pos[c * 3 + 1] - cy;
        float dz = pos[c * 3 + 2] - cz;
        float nrm = sqrtf(dx * dx + dy * dy + dz * dz);
        float inv = 1.0f / (nrm + 1e-8f);
        dsx += dx * inv;
        dsy += dy * inv;
        dsz += dz * inv;
    }
    const float S3 = 0.57735026918962576f;
    const float sx[8] = {1, -1, 1, 1, -1, -1, 1, -1};
    const float sy[8] = {1, 1, -1, 1, -1, 1, -1, -1};
    const float sz[8] = {1, 1, 1, -1, 1, -1, -1, -1};
    float sc[3] = {lkb[0], lkb[1], lkb[2]};
#pragma unroll
    for (int j = 0; j < 8; ++j) {
        float nb = (sx[j] * dsx + sy[j] * dsy + sz[j] * dsz) * (S3 * (1.0f / 16.0f));
        sc[0] += nb * lkw[j * 3 + 0];
        sc[1] += nb * lkw[j * 3 + 1];
        sc[2] += nb * lkw[j * 3 + 2];
    }
    float m = (sc[0] + sc[1] + sc[2]) * (1.0f / 3.0f);
    float v = ((sc[0] - m) * (sc[0] - m) + (sc[1] - m) * (sc[1] - m) +
               (sc[2] - m) * (sc[2] - m)) * (1.0f / 3.0f);
    float rstd = rsqrtf(fmaxf(v, 0.0f) + 1e-5f);
#pragma unroll
    for (int c = 0; c < 3; ++c)
        sfeat[r * 3 + c] = (sc[c] - m) * rstd * lng[c] + lnb[c];
}

// ---------------------------------------------------------------- edge MLP + segment max (MFMA)
__global__ __launch_bounds__(256) void k_edge(const float* __restrict__ pos,
                                              const float* __restrict__ refl,
                                              const int* __restrict__ idxp,
                                              const int* __restrict__ colp,
                                              const u16* __restrict__ xfeat,
                                              const float* __restrict__ sfeat,
                                              const u16* __restrict__ w1t,
                                              const float* __restrict__ b1,
                                              const u16* __restrict__ w2t,
                                              const float* __restrict__ b2,
                                              float* __restrict__ agg,
                                              u16* __restrict__ aggb) {
    __shared__ u16 uni16[128 * 72];   // msg bf16, then w2t
    __shared__ u16 hs[128 * 72];
    __shared__ u16 w1s[64 * 72];
    __shared__ float b1s[64];
    __shared__ float b2s[128];
    int t = threadIdx.x;
    int r0 = blockIdx.x * 8;
    long e0 = (long)r0 * 16;
    int wave = t >> 6, lane = t & 63;
    int quad = lane >> 4, l16 = lane & 15;
    int mt0 = wave * 2;

    for (int u = t; u < 512; u += 256) {
        int row = u >> 3, c8 = (u & 7) * 8;
        *(uint4*)(&w1s[row * 72 + c8]) = *(const uint4*)(w1t + row * 64 + c8);
    }
    if (t < 64) b1s[t] = b1[t];
    if (t < 128) b2s[t] = b2[t];

    for (int u = t; u < 512; u += 256) {
        int e = u >> 2, seg = u & 3;
        int c = colp[e0 + e];
        uint4 d = *(const uint4*)(xfeat + (long)c * 32 + seg * 8);
        *(uint4*)(&uni16[e * 72 + seg * 8]) = d;
    }
    if (t < 128) {
        int e = t;
        int r = r0 + (e >> 4);
        int c = colp[e0 + e];
        int ci = idxp[r];
        u16 tmp[8];
        tmp[0] = f2b(pos[c * 3 + 0] - pos[ci * 3 + 0]);
        tmp[1] = f2b(pos[c * 3 + 1] - pos[ci * 3 + 1]);
        tmp[2] = f2b(pos[c * 3 + 2] - pos[ci * 3 + 2]);
        tmp[3] = f2b(refl[c] - refl[ci]);
        tmp[4] = f2b(sfeat[r * 3 + 0]);
        tmp[5] = f2b(sfeat[r * 3 + 1]);
        tmp[6] = f2b(sfeat[r * 3 + 2]);
        tmp[7] = 0;
        *(uint4*)(&uni16[e * 72 + 32]) = *(uint4*)tmp;
        uint4 z = {0, 0, 0, 0};
        *(uint4*)(&uni16[e * 72 + 40]) = z;
        *(uint4*)(&uni16[e * 72 + 48]) = z;
        *(uint4*)(&uni16[e * 72 + 56]) = z;
    }
    __syncthreads();

    {
        f32x4 acc[2][4];
#pragma unroll
        for (int i = 0; i < 2; ++i)
#pragma unroll
            for (int j = 0; j < 4; ++j) acc[i][j] = (f32x4){0.f, 0.f, 0.f, 0.f};
#pragma unroll
        for (int kk = 0; kk < 64; kk += 32) {
            u16x8 af[2], bfr[4];
#pragma unroll
            for (int i = 0; i < 2; ++i)
                af[i] = *(const u16x8*)(&uni16[((mt0 + i) * 16 + l16) * 72 + kk + quad * 8]);
#pragma unroll
            for (int j = 0; j < 4; ++j)
                bfr[j] = *(const u16x8*)(&w1s[(j * 16 + l16) * 72 + kk + quad * 8]);
#pragma unroll
            for (int i = 0; i < 2; ++i)
#pragma unroll
                for (int j = 0; j < 4; ++j)
                    acc[i][j] = mfma_bf16(af[i], bfr[j], acc[i][j]);
        }
#pragma unroll
        for (int i = 0; i < 2; ++i)
#pragma unroll
            for (int j = 0; j < 4; ++j) {
                f32x4 c = acc_fence(acc[i][j]);
                int n = j * 16 + l16;
#pragma unroll
                for (int r = 0; r < 4; ++r) {
                    float v = silu_f(BNCF * (c[r] + b1s[n]));
                    hs[((mt0 + i) * 16 + quad * 4 + r) * 72 + n] = f2b(v);
                }
            }
    }
    __syncthreads();

    for (int u = t; u < 1024; u += 256) {
        int row = u >> 3, c8 = (u & 7) * 8;
        *(uint4*)(&uni16[row * 72 + c8]) = *(const uint4*)(w2t + row * 64 + c8);
    }
    __syncthreads();

    {
        f32x4 acc[2][8];
#pragma unroll
        for (int i = 0; i < 2; ++i)
#pragma unroll
            for (int j = 0; j < 8; ++j) acc[i][j] = (f32x4){0.f, 0.f, 0.f, 0.f};
#pragma unroll
        for (int kk = 0; kk < 64; kk += 32) {
            u16x8 af[2], bfr[8];
#pragma unroll
            for (int i = 0; i < 2; ++i)
                af[i] = *(const u16x8*)(&hs[((mt0 + i) * 16 + l16) * 72 + kk + quad * 8]);
#pragma unroll
            for (int j = 0; j < 8; ++j)
                bfr[j] = *(const u16x8*)(&uni16[(j * 16 + l16) * 72 + kk + quad * 8]);
#pragma unroll
            for (int i = 0; i < 2; ++i)
#pragma unroll
                for (int j = 0; j < 8; ++j)
                    acc[i][j] = mfma_bf16(af[i], bfr[j], acc[i][j]);
        }
#pragma unroll
        for (int i = 0; i < 2; ++i) {
            int rg = r0 + mt0 + i;
#pragma unroll
            for (int j = 0; j < 8; ++j) {
                f32x4 c = acc_fence(acc[i][j]);
                int n = j * 16 + l16;
                float mx = -1e30f;
#pragma unroll
                for (int r = 0; r < 4; ++r)
                    mx = fmaxf(mx, silu_f(BNCF * (c[r] + b2s[n])));
                mx = fmaxf(mx, __shfl_xor(mx, 16));
                mx = fmaxf(mx, __shfl_xor(mx, 32));
                if (quad == 0) {
                    agg[(long)rg * 128 + n] = mx;
                    aggb[(long)rg * 128 + n] = f2b(mx);
                }
            }
        }
    }
}

// ---------------------------------------------------------------- MFMA GEMM
template <int EPI, int OD>
__global__ __launch_bounds__(256) void k_mgemm(const u16* __restrict__ A,
                                               const u16* __restrict__ Bt,
                                               const float* __restrict__ bias,
                                               const float* __restrict__ dww,
                                               const float* __restrict__ dwb,
                                               const float* __restrict__ res,
                                               void* __restrict__ Ov,
                                               int K, int Nn) {
    __shared__ u16 As[128][72];
    __shared__ u16 Bs[128][72];
    int t = threadIdx.x;
    int wave = t >> 6, lane = t & 63;
    int quad = lane >> 4, l16 = lane & 15;
    int R0 = blockIdx.y * 128, C0 = blockIdx.x * 128;
    int wm = (wave & 1) * 64, wn = (wave >> 1) * 64;

    f32x4 acc[4][4];
#pragma unroll
    for (int i = 0; i < 4; ++i)
#pragma unroll
        for (int j = 0; j < 4; ++j) acc[i][j] = (f32x4){0.f, 0.f, 0.f, 0.f};

    for (int k0 = 0; k0 < K; k0 += 64) {
#pragma unroll
        for (int u = t; u < 1024; u += 256) {
            int row = u >> 3, c8 = (u & 7) * 8;
            uint4 v = *(const uint4*)(A + (long)(R0 + row) * K + k0 + c8);
            *(uint4*)(&As[row][c8]) = v;
        }
#pragma unroll
        for (int u = t; u < 1024; u += 256) {
            int row = u >> 3, c8 = (u & 7) * 8;
            uint4 v = *(const uint4*)(Bt + (long)(C0 + row) * K + k0 + c8);
            *(uint4*)(&Bs[row][c8]) = v;
        }
        __syncthreads();
#pragma unroll
        for (int kk = 0; kk < 64; kk += 32) {
            u16x8 af[4], bfr[4];
#pragma unroll
            for (int tm = 0; tm < 4; ++tm)
                af[tm] = *(const u16x8*)(&As[wm + tm * 16 + l16][kk + quad * 8]);
#pragma unroll
            for (int tn = 0; tn < 4; ++tn)
                bfr[tn] = *(const u16x8*)(&Bs[wn + tn * 16 + l16][kk + quad * 8]);
#pragma unroll
            for (int tm = 0; tm < 4; ++tm)
#pragma unroll
                for (int tn = 0; tn < 4; ++tn)
                    acc[tm][tn] = mfma_bf16(af[tm], bfr[tn], acc[tm][tn]);
        }
        __syncthreads();
    }

#pragma unroll
    for (int tm = 0; tm < 4; ++tm) {
#pragma unroll
        for (int tn = 0; tn < 4; ++tn) {
            f32x4 c = acc_fence(acc[tm][tn]);
            int n = C0 + wn + tn * 16 + l16;
#pragma unroll
            for (int r = 0; r < 4; ++r) {
                int m = R0 + wm + tm * 16 + quad * 4 + r;
                float v = c[r];
                if (EPI == 0) {
                    v = silu_f(BNCF * (v + bias[n]));
                    v = silu_f(BNCF * (v * dww[n] + dwb[n]));
                } else if (EPI == 1) {
                    v = silu_f(BNCF * (v + bias[n]));
                    v = silu_f(BNCF * v);
                    v = silu_f(BNCF * (v * dww[n] + dwb[n]));
                } else if (EPI == 2) {
                    v = silu_f(BNCF * (v + bias[n]));
                    v = BNCF * v;
                } else {
                    v = BNCF * (v + bias[n]);
                    v = silu_f(v + res[(long)m * 128 + n]);
                }
                if (OD == 0)
                    ((u16*)Ov)[(long)m * Nn + n] = f2b(v);
                else
                    ((float*)Ov)[(long)m * Nn + n] = v;
            }
        }
    }
}

// ---------------------------------------------------------------- launcher
extern "C" void kernel_launch(void* const* d_in, const int* in_sizes, int n_in,
                              void* d_out, int out_size, void* d_ws, size_t ws_size,
                              hipStream_t stream) {
    const float* pos   = (const float*)d_in[0];
    const float* refl  = (const float*)d_in[1];
    const float* sfv   = (const float*)d_in[2];
    const int*   batch = (const int*)d_in[3];
    const int*   idxp  = (const int*)d_in[4];
    const int*   colp  = (const int*)d_in[5];
    const float* s_g  = (const float*)d_in[7];
    const float* s_b  = (const float*)d_in[8];
    const float* s_w1 = (const float*)d_in[9];
    const float* s_b1 = (const float*)d_in[10];
    const float* s_w2 = (const float*)d_in[11];
    const float* s_b2 = (const float*)d_in[12];
    const float* lkw  = (const float*)d_in[13];
    const float* lkb  = (const float*)d_in[14];
    const float* lng  = (const float*)d_in[15];
    const float* lnb  = (const float*)d_in[16];
    const float* l_w1 = (const float*)d_in[17];
    const float* l_b1 = (const float*)d_in[18];
    const float* l_w2 = (const float*)d_in[19];
    const float* l_b2 = (const float*)d_in[20];
    const float* expw = (const float*)d_in[21];
    const float* expb = (const float*)d_in[22];
    const float* dw1w = (const float*)d_in[23];
    const float* dw1b = (const float*)d_in[24];
    const float* pw1w = (const float*)d_in[25];
    const float* pw1b = (const float*)d_in[26];
    const float* dw2w = (const float*)d_in[27];
    const float* dw2b = (const float*)d_in[28];
    const float* pw2w = (const float*)d_in[29];
    const float* pw2b = (const float*)d_in[30];
    const float* prjw = (const float*)d_in[31];
    const float* prjb = (const float*)d_in[32];

    char* ws = (char*)d_ws;
    float* cent  = (float*)(ws + 0);                  // 64 B
    float* sfeat = (float*)(ws + 64);                 // M*3*4
    float* agg   = (float*)(ws + 393280);             // M*128*4 f32
    u16*   aggb  = (u16*)(ws + 17170496);             // M*128*2 bf16
    u16*   u1    = (u16*)(ws + 25559104);             // M*512*2
    u16*   u2    = (u16*)(ws + 59113536);             // M*512*2
    u16*   xf    = (u16*)(ws + 59113536);             // N*32*2 (aliases u2; dead before u2 written)
    u16*   expwt = (u16*)(ws + 92667968);             // 512*128*2
    u16*   pw1t  = (u16*)(ws + 92799040);             // 512*512*2
    u16*   pw2t  = (u16*)(ws + 93323328);             // 512*512*2
    u16*   prjt  = (u16*)(ws + 93847616);             // 128*512*2
    u16*   lw1t  = (u16*)(ws + 93978688);             // 64*64*2   = 8192
    u16*   lw2t  = (u16*)(ws + 93986880);             // 128*64*2  = 16384
    u16*   sw1t  = (u16*)(ws + 94003264);             // 64*128*2  = 16384
    u16*   sw2t  = (u16*)(ws + 94019648);             // 32*64*2   = 4096

    k_prep<<<2648, 256, 0, stream>>>(expw, expwt, pw1w, pw1t, pw2w, pw2t,
                                     prjw, prjt, l_w1, lw1t, l_w2, lw2t,
                                     s_w1, sw1t, s_w2, sw2t);

    hipMemsetAsync(cent, 0, 64, stream);
    k_centers<<<512, 256, 0, stream>>>(pos, sfv, batch, cent);
    k_stem<<<1024, 256, 0, stream>>>(pos, refl, sfv, batch, cent, s_g, s_b,
                                     sw1t, s_b1, sw2t, s_b2, xf);
    k_sfeat<<<128, 256, 0, stream>>>(pos, idxp, colp, lkw, lkb, lng, lnb, sfeat);
    k_edge<<<4096, 256, 0, stream>>>(pos, refl, idxp, colp, xf, sfeat,
                                     lw1t, l_b1, lw2t, l_b2, agg, aggb);

    dim3 blk(256);
    k_mgemm<0, 0><<<dim3(4, 256), blk, 0, stream>>>(aggb, expwt, expb, dw1w, dw1b,
                                                    nullptr, u1, 128, 512);
    k_mgemm<1, 0><<<dim3(4, 256), blk, 0, stream>>>(u1, pw1t, pw1b, dw2w, dw2b,
                                                    nullptr, u2, 512, 512);
    k_mgemm<2, 0><<<dim3(4, 256), blk, 0, stream>>>(u2, pw2t, pw2b, nullptr, nullptr,
                                                    nullptr, u1, 512, 512);
    k_mgemm<3, 1><<<dim3(1, 256), blk, 0, stream>>>(u1, prjt, prjb, nullptr, nullptr,
                                                    agg, d_out, 512, 128);
}

// Round 9
// 425.064 us; speedup vs baseline: 2.6557x; 1.0181x over previous
//
#include <hip/hip_runtime.h>

typedef unsigned short u16;
typedef unsigned int   u32;
typedef __attribute__((ext_vector_type(8))) u16  u16x8;
typedef __attribute__((ext_vector_type(4))) float f32x4;

#define N_PTS   131072
#define M_PTS   32768
#define BNCF    0.9999950000374997f

__device__ __forceinline__ float b2f(u16 u) {
    u32 x = ((u32)u) << 16;
    float f;
    __builtin_memcpy(&f, &x, 4);
    return f;
}
__device__ __forceinline__ u16 f2b(float f) {
    u32 x;
    __builtin_memcpy(&x, &f, 4);
    u32 r = x + 0x7fffu + ((x >> 16) & 1u);
    return (u16)(r >> 16);
}
__device__ __forceinline__ float silu_f(float x) {
    return x / (1.0f + __expf(-x));
}

__device__ __forceinline__ f32x4 mfma_bf16(u16x8 a, u16x8 b, f32x4 c) {
    asm volatile("v_mfma_f32_16x16x32_bf16 %0, %1, %2, %0"
                 : "+v"(c) : "v"(a), "v"(b));
    return c;
}
// MAI->VALU wait-state guard.
__device__ __forceinline__ f32x4 acc_fence(f32x4 c) {
    asm volatile("s_nop 7\n\ts_nop 7\n\ts_nop 3" : "+v"(c));
    return c;
}

// ---------------------------------------------------------------- all weight transposes in ONE dispatch
__global__ __launch_bounds__(256) void k_prep(const float* __restrict__ expw, u16* __restrict__ expwt,
                                              const float* __restrict__ pw1w, u16* __restrict__ pw1t,
                                              const float* __restrict__ pw2w, u16* __restrict__ pw2t,
                                              const float* __restrict__ prjw, u16* __restrict__ prjt,
                                              const float* __restrict__ lw1,  u16* __restrict__ lw1t,
                                              const float* __restrict__ lw2,  u16* __restrict__ lw2t,
                                              const float* __restrict__ sw1,  u16* __restrict__ sw1t,
                                              const float* __restrict__ sw2,  u16* __restrict__ sw2t) {
    int idx = blockIdx.x * 256 + threadIdx.x;
    const float* W; u16* O; int K, Kp, Nn;
    if (idx < 65536)                 { W = expw; O = expwt; K = 128; Kp = 128; Nn = 512; }
    else if ((idx -= 65536) < 262144){ W = pw1w; O = pw1t;  K = 512; Kp = 512; Nn = 512; }
    else if ((idx -= 262144) < 262144){ W = pw2w; O = pw2t; K = 512; Kp = 512; Nn = 512; }
    else if ((idx -= 262144) < 65536){ W = prjw; O = prjt;  K = 512; Kp = 512; Nn = 128; }
    else if ((idx -= 65536) < 4096)  { W = lw1;  O = lw1t;  K = 39;  Kp = 64;  Nn = 64;  }
    else if ((idx -= 4096) < 8192)   { W = lw2;  O = lw2t;  K = 64;  Kp = 64;  Nn = 128; }
    else if ((idx -= 8192) < 8192)   { W = sw1;  O = sw1t;  K = 97;  Kp = 128; Nn = 64;  }
    else if ((idx -= 8192) < 2048)   { W = sw2;  O = sw2t;  K = 64;  Kp = 64;  Nn = 32;  }
    else return;
    int n = idx / Kp, k = idx % Kp;
    O[idx] = (k < K) ? f2b(W[(long)k * Nn + n]) : (u16)0;
}

// ---------------------------------------------------------------- centers
__global__ __launch_bounds__(256) void k_centers(const float* __restrict__ pos,
                                                 const float* __restrict__ sfv,
                                                 const int* __restrict__ batch,
                                                 float* __restrict__ acc) {
    __shared__ float ls[16];
    int t = threadIdx.x;
    if (t < 16) ls[t] = 0.0f;
    __syncthreads();
    int i = blockIdx.x * 256 + t;
    if (i < N_PTS) {
        int b = batch[i];
        float inv = 1.0f / sfv[b];
        atomicAdd(&ls[b * 4 + 0], pos[i * 3 + 0] * inv);
        atomicAdd(&ls[b * 4 + 1], pos[i * 3 + 1] * inv);
        atomicAdd(&ls[b * 4 + 2], pos[i * 3 + 2] * inv);
        atomicAdd(&ls[b * 4 + 3], 1.0f);
    }
    __syncthreads();
    if (t < 16) atomicAdd(&acc[t], ls[t]);
}

// ---------------------------------------------------------------- stem (MFMA)
__global__ __launch_bounds__(256) void k_stem(const float* __restrict__ pos,
                                              const float* __restrict__ refl,
                                              const float* __restrict__ sfv,
                                              const int* __restrict__ batch,
                                              const float* __restrict__ cacc,
                                              const float* __restrict__ g,
                                              const float* __restrict__ bb,
                                              const u16* __restrict__ w1t,   // [64][128] bf16 (zero pad k>=97)
                                              const float* __restrict__ b1,
                                              const u16* __restrict__ w2t,   // [32][64] bf16
                                              const float* __restrict__ b2,
                                              u16* __restrict__ xout) {
    __shared__ u16 xs[128][136];
    __shared__ u16 hb[128][72];
    __shared__ u16 w1s[64][136];
    __shared__ u16 w2s[32][72];
    __shared__ float b1s[64];
    __shared__ float b2s[32];
    const float FREQS[16] = {
        1.0f, 0.31622776601683794f, 0.1f, 0.031622776601683791f,
        0.01f, 0.0031622776601683794f, 0.001f, 0.00031622776601683794f,
        0.0001f, 3.1622776601683795e-05f, 1e-05f, 3.1622776601683796e-06f,
        1e-06f, 3.1622776601683797e-07f, 1e-07f, 3.1622776601683792e-08f};
    int t = threadIdx.x;
    int wave = t >> 6, lane = t & 63;
    int quad = lane >> 4, l16 = lane & 15;
    int mt0 = wave * 2;

    // zero ALL of xs: 128*136 u16 = 2176 uint4 (was 1088 — R5-R8 latent bug:
    // rows 64..127 pad cols read uninitialized LDS, nondeterministic corruption)
    for (int u = t; u < 2176; u += 256) ((uint4*)xs)[u] = (uint4){0, 0, 0, 0};
    for (int u = t; u < 1024; u += 256) {
        int row = u >> 4, c8 = (u & 15) * 8;
        *(uint4*)(&w1s[row][c8]) = *(const uint4*)(w1t + row * 128 + c8);
    }
    {
        int row = t >> 3, c8 = (t & 7) * 8;
        *(uint4*)(&w2s[row][c8]) = *(const uint4*)(w2t + row * 64 + c8);
    }
    if (t < 64) b1s[t] = b1[t];
    if (t < 32) b2s[t] = b2[t];
    __syncthreads();

    if (t < 128) {
        int i = blockIdx.x * 128 + t;
        int b = batch[i];
        float s = 1.0f / sfv[b];
        float cnt = fmaxf(cacc[b * 4 + 3], 1.0f);
        float npv[3];
#pragma unroll
        for (int d = 0; d < 3; ++d)
            npv[d] = pos[i * 3 + d] * s - cacc[b * 4 + d] / cnt;

        float sum = 0.0f, sq = 0.0f;
#pragma unroll
        for (int d = 0; d < 3; ++d) {
#pragma unroll
            for (int f = 0; f < 16; ++f) {
                float a = npv[d] * FREQS[f];
                float sv, cv;
                __sincosf(a, &sv, &cv);
                sum += sv + cv;
                sq += sv * sv + cv * cv;
                xs[t][d * 32 + f] = f2b(sv);
                xs[t][d * 32 + 16 + f] = f2b(cv);
            }
        }
        float rf = refl[i];
        sum += rf;
        sq += rf * rf;
        xs[t][96] = f2b(rf);

        float m = sum * (1.0f / 97.0f);
        float var = sq * (1.0f / 97.0f) - m * m;
        float rstd = rsqrtf(fmaxf(var, 0.0f) + 1e-5f);
        for (int k = 0; k < 97; ++k) {
            float v = b2f(xs[t][k]);
            xs[t][k] = f2b((v - m) * rstd * g[k] + bb[k]);
        }
    }
    __syncthreads();

    {
        f32x4 acc[2][4];
#pragma unroll
        for (int i = 0; i < 2; ++i)
#pragma unroll
            for (int j = 0; j < 4; ++j) acc[i][j] = (f32x4){0.f, 0.f, 0.f, 0.f};
#pragma unroll
        for (int kk = 0; kk < 128; kk += 32) {
            u16x8 af[2], bfr[4];
#pragma unroll
            for (int i = 0; i < 2; ++i)
                af[i] = *(const u16x8*)(&xs[(mt0 + i) * 16 + l16][kk + quad * 8]);
#pragma unroll
            for (int j = 0; j < 4; ++j)
                bfr[j] = *(const u16x8*)(&w1s[j * 16 + l16][kk + quad * 8]);
#pragma unroll
            for (int i = 0; i < 2; ++i)
#pragma unroll
                for (int j = 0; j < 4; ++j)
                    acc[i][j] = mfma_bf16(af[i], bfr[j], acc[i][j]);
        }
#pragma unroll
        for (int i = 0; i < 2; ++i)
#pragma unroll
            for (int j = 0; j < 4; ++j) {
                f32x4 c = acc_fence(acc[i][j]);
                int n = j * 16 + l16;
#pragma unroll
                for (int r = 0; r < 4; ++r)
                    hb[(mt0 + i) * 16 + quad * 4 + r][n] =
                        f2b(silu_f(BNCF * (c[r] + b1s[n])));
            }
    }
    __syncthreads();

    {
        f32x4 acc[2][2];
#pragma unroll
        for (int i = 0; i < 2; ++i)
#pragma unroll
            for (int j = 0; j < 2; ++j) acc[i][j] = (f32x4){0.f, 0.f, 0.f, 0.f};
#pragma unroll
        for (int kk = 0; kk < 64; kk += 32) {
            u16x8 af[2], bfr[2];
#pragma unroll
            for (int i = 0; i < 2; ++i)
                af[i] = *(const u16x8*)(&hb[(mt0 + i) * 16 + l16][kk + quad * 8]);
#pragma unroll
            for (int j = 0; j < 2; ++j)
                bfr[j] = *(const u16x8*)(&w2s[j * 16 + l16][kk + quad * 8]);
#pragma unroll
            for (int i = 0; i < 2; ++i)
#pragma unroll
                for (int j = 0; j < 2; ++j)
                    acc[i][j] = mfma_bf16(af[i], bfr[j], acc[i][j]);
        }
#pragma unroll
        for (int i = 0; i < 2; ++i)
#pragma unroll
            for (int j = 0; j < 2; ++j) {
                f32x4 c = acc_fence(acc[i][j]);
                int n = j * 16 + l16;
#pragma unroll
                for (int r = 0; r < 4; ++r) {
                    int m = (mt0 + i) * 16 + quad * 4 + r;
                    long ig = (long)blockIdx.x * 128 + m;
                    xout[ig * 32 + n] = f2b(silu_f(BNCF * (c[r] + b2s[n])));
                }
            }
    }
}

// ---------------------------------------------------------------- sfeat
__global__ __launch_bounds__(256) void k_sfeat(const float* __restrict__ pos,
                                               const int* __restrict__ idxp,
                                               const int* __restrict__ colp,
                                               const float* __restrict__ lkw,
                                               const float* __restrict__ lkb,
                                               const float* __restrict__ lng,
                                               const float* __restrict__ lnb,
                                               float* __restrict__ sfeat) {
    int r = blockIdx.x * 256 + threadIdx.x;
    if (r >= M_PTS) return;
    int ci = idxp[r];
    float cx = pos[ci * 3 + 0];
    float cy = pos[ci * 3 + 1];
    float cz = pos[ci * 3 + 2];
    float dsx = 0.0f, dsy = 0.0f, dsz = 0.0f;
    for (int e = 0; e < 16; ++e) {
        int c = colp[r * 16 + e];
        float dx = pos[c * 3 + 0] - cx;
        float dy = pos[c * 3 + 1] - cy;
        float dz = pos[c * 3 + 2] - cz;
        float nrm = sqrtf(dx * dx + dy * dy + dz * dz);
        float inv = 1.0f / (nrm + 1e-8f);
        dsx += dx * inv;
        dsy += dy * inv;
        dsz += dz * inv;
    }
    const float S3 = 0.57735026918962576f;
    const float sx[8] = {1, -1, 1, 1, -1, -1, 1, -1};
    const float sy[8] = {1, 1, -1, 1, -1, 1, -1, -1};
    const float sz[8] = {1, 1, 1, -1, 1, -1, -1, -1};
    float sc[3] = {lkb[0], lkb[1], lkb[2]};
#pragma unroll
    for (int j = 0; j < 8; ++j) {
        float nb = (sx[j] * dsx + sy[j] * dsy + sz[j] * dsz) * (S3 * (1.0f / 16.0f));
        sc[0] += nb * lkw[j * 3 + 0];
        sc[1] += nb * lkw[j * 3 + 1];
        sc[2] += nb * lkw[j * 3 + 2];
    }
    float m = (sc[0] + sc[1] + sc[2]) * (1.0f / 3.0f);
    float v = ((sc[0] - m) * (sc[0] - m) + (sc[1] - m) * (sc[1] - m) +
               (sc[2] - m) * (sc[2] - m)) * (1.0f / 3.0f);
    float rstd = rsqrtf(fmaxf(v, 0.0f) + 1e-5f);
#pragma unroll
    for (int c = 0; c < 3; ++c)
        sfeat[r * 3 + c] = (sc[c] - m) * rstd * lng[c] + lnb[c];
}

// ---------------------------------------------------------------- edge MLP + segment max (MFMA)
__global__ __launch_bounds__(256) void k_edge(const float* __restrict__ pos,
                                              const float* __restrict__ refl,
                                              const int* __restrict__ idxp,
                                              const int* __restrict__ colp,
                                              const u16* __restrict__ xfeat,
                                              const float* __restrict__ sfeat,
                                              const u16* __restrict__ w1t,
                                              const float* __restrict__ b1,
                                              const u16* __restrict__ w2t,
                                              const float* __restrict__ b2,
                                              float* __restrict__ agg,
                                              u16* __restrict__ aggb) {
    __shared__ u16 uni16[128 * 72];   // msg bf16, then w2t
    __shared__ u16 hs[128 * 72];
    __shared__ u16 w1s[64 * 72];
    __shared__ float b1s[64];
    __shared__ float b2s[128];
    int t = threadIdx.x;
    int r0 = blockIdx.x * 8;
    long e0 = (long)r0 * 16;
    int wave = t >> 6, lane = t & 63;
    int quad = lane >> 4, l16 = lane & 15;
    int mt0 = wave * 2;

    for (int u = t; u < 512; u += 256) {
        int row = u >> 3, c8 = (u & 7) * 8;
        *(uint4*)(&w1s[row * 72 + c8]) = *(const uint4*)(w1t + row * 64 + c8);
    }
    if (t < 64) b1s[t] = b1[t];
    if (t < 128) b2s[t] = b2[t];

    for (int u = t; u < 512; u += 256) {
        int e = u >> 2, seg = u & 3;
        int c = colp[e0 + e];
        uint4 d = *(const uint4*)(xfeat + (long)c * 32 + seg * 8);
        *(uint4*)(&uni16[e * 72 + seg * 8]) = d;
    }
    if (t < 128) {
        int e = t;
        int r = r0 + (e >> 4);
        int c = colp[e0 + e];
        int ci = idxp[r];
        u16 tmp[8];
        tmp[0] = f2b(pos[c * 3 + 0] - pos[ci * 3 + 0]);
        tmp[1] = f2b(pos[c * 3 + 1] - pos[ci * 3 + 1]);
        tmp[2] = f2b(pos[c * 3 + 2] - pos[ci * 3 + 2]);
        tmp[3] = f2b(refl[c] - refl[ci]);
        tmp[4] = f2b(sfeat[r * 3 + 0]);
        tmp[5] = f2b(sfeat[r * 3 + 1]);
        tmp[6] = f2b(sfeat[r * 3 + 2]);
        tmp[7] = 0;
        *(uint4*)(&uni16[e * 72 + 32]) = *(uint4*)tmp;
        uint4 z = {0, 0, 0, 0};
        *(uint4*)(&uni16[e * 72 + 40]) = z;
        *(uint4*)(&uni16[e * 72 + 48]) = z;
        *(uint4*)(&uni16[e * 72 + 56]) = z;
    }
    __syncthreads();

    {
        f32x4 acc[2][4];
#pragma unroll
        for (int i = 0; i < 2; ++i)
#pragma unroll
            for (int j = 0; j < 4; ++j) acc[i][j] = (f32x4){0.f, 0.f, 0.f, 0.f};
#pragma unroll
        for (int kk = 0; kk < 64; kk += 32) {
            u16x8 af[2], bfr[4];
#pragma unroll
            for (int i = 0; i < 2; ++i)
                af[i] = *(const u16x8*)(&uni16[((mt0 + i) * 16 + l16) * 72 + kk + quad * 8]);
#pragma unroll
            for (int j = 0; j < 4; ++j)
                bfr[j] = *(const u16x8*)(&w1s[(j * 16 + l16) * 72 + kk + quad * 8]);
#pragma unroll
            for (int i = 0; i < 2; ++i)
#pragma unroll
                for (int j = 0; j < 4; ++j)
                    acc[i][j] = mfma_bf16(af[i], bfr[j], acc[i][j]);
        }
#pragma unroll
        for (int i = 0; i < 2; ++i)
#pragma unroll
            for (int j = 0; j < 4; ++j) {
                f32x4 c = acc_fence(acc[i][j]);
                int n = j * 16 + l16;
#pragma unroll
                for (int r = 0; r < 4; ++r) {
                    float v = silu_f(BNCF * (c[r] + b1s[n]));
                    hs[((mt0 + i) * 16 + quad * 4 + r) * 72 + n] = f2b(v);
                }
            }
    }
    __syncthreads();

    for (int u = t; u < 1024; u += 256) {
        int row = u >> 3, c8 = (u & 7) * 8;
        *(uint4*)(&uni16[row * 72 + c8]) = *(const uint4*)(w2t + row * 64 + c8);
    }
    __syncthreads();

    {
        f32x4 acc[2][8];
#pragma unroll
        for (int i = 0; i < 2; ++i)
#pragma unroll
            for (int j = 0; j < 8; ++j) acc[i][j] = (f32x4){0.f, 0.f, 0.f, 0.f};
#pragma unroll
        for (int kk = 0; kk < 64; kk += 32) {
            u16x8 af[2], bfr[8];
#pragma unroll
            for (int i = 0; i < 2; ++i)
                af[i] = *(const u16x8*)(&hs[((mt0 + i) * 16 + l16) * 72 + kk + quad * 8]);
#pragma unroll
            for (int j = 0; j < 8; ++j)
                bfr[j] = *(const u16x8*)(&uni16[(j * 16 + l16) * 72 + kk + quad * 8]);
#pragma unroll
            for (int i = 0; i < 2; ++i)
#pragma unroll
                for (int j = 0; j < 8; ++j)
                    acc[i][j] = mfma_bf16(af[i], bfr[j], acc[i][j]);
        }
        // silu is decreasing then increasing (min at x*=-1.2785):
        // max_e silu(x_e) == max(silu(max x), silu(min x)); BNCF>0 keeps order.
#pragma unroll
        for (int i = 0; i < 2; ++i) {
            int rg = r0 + mt0 + i;
#pragma unroll
            for (int j = 0; j < 8; ++j) {
                f32x4 c = acc_fence(acc[i][j]);
                int n = j * 16 + l16;
                float mx = fmaxf(fmaxf(c[0], c[1]), fmaxf(c[2], c[3]));
                float mn = fminf(fminf(c[0], c[1]), fminf(c[2], c[3]));
                mx = fmaxf(mx, __shfl_xor(mx, 16));
                mx = fmaxf(mx, __shfl_xor(mx, 32));
                mn = fminf(mn, __shfl_xor(mn, 16));
                mn = fminf(mn, __shfl_xor(mn, 32));
                if (quad == 0) {
                    float v = fmaxf(silu_f(BNCF * (mx + b2s[n])),
                                    silu_f(BNCF * (mn + b2s[n])));
                    agg[(long)rg * 128 + n] = v;
                    aggb[(long)rg * 128 + n] = f2b(v);
                }
            }
        }
    }
}

// ---------------------------------------------------------------- MFMA GEMM (proven staging)
template <int EPI, int OD>
__global__ __launch_bounds__(256) void k_mgemm(const u16* __restrict__ A,
                                               const u16* __restrict__ Bt,
                                               const float* __restrict__ bias,
                                               const float* __restrict__ dww,
                                               const float* __restrict__ dwb,
                                               const float* __restrict__ res,
                                               void* __restrict__ Ov,
                                               int K, int Nn) {
    __shared__ u16 As[128][72];
    __shared__ u16 Bs[128][72];
    int t = threadIdx.x;
    int wave = t >> 6, lane = t & 63;
    int quad = lane >> 4, l16 = lane & 15;
    int R0 = blockIdx.y * 128, C0 = blockIdx.x * 128;
    int wm = (wave & 1) * 64, wn = (wave >> 1) * 64;

    f32x4 acc[4][4];
#pragma unroll
    for (int i = 0; i < 4; ++i)
#pragma unroll
        for (int j = 0; j < 4; ++j) acc[i][j] = (f32x4){0.f, 0.f, 0.f, 0.f};

    for (int k0 = 0; k0 < K; k0 += 64) {
#pragma unroll
        for (int u = t; u < 1024; u += 256) {
            int row = u >> 3, c8 = (u & 7) * 8;
            uint4 v = *(const uint4*)(A + (long)(R0 + row) * K + k0 + c8);
            *(uint4*)(&As[row][c8]) = v;
        }
#pragma unroll
        for (int u = t; u < 1024; u += 256) {
            int row = u >> 3, c8 = (u & 7) * 8;
            uint4 v = *(const uint4*)(Bt + (long)(C0 + row) * K + k0 + c8);
            *(uint4*)(&Bs[row][c8]) = v;
        }
        __syncthreads();
#pragma unroll
        for (int kk = 0; kk < 64; kk += 32) {
            u16x8 af[4], bfr[4];
#pragma unroll
            for (int tm = 0; tm < 4; ++tm)
                af[tm] = *(const u16x8*)(&As[wm + tm * 16 + l16][kk + quad * 8]);
#pragma unroll
            for (int tn = 0; tn < 4; ++tn)
                bfr[tn] = *(const u16x8*)(&Bs[wn + tn * 16 + l16][kk + quad * 8]);
#pragma unroll
            for (int tm = 0; tm < 4; ++tm)
#pragma unroll
                for (int tn = 0; tn < 4; ++tn)
                    acc[tm][tn] = mfma_bf16(af[tm], bfr[tn], acc[tm][tn]);
        }
        __syncthreads();
    }

#pragma unroll
    for (int tm = 0; tm < 4; ++tm) {
#pragma unroll
        for (int tn = 0; tn < 4; ++tn) {
            f32x4 c = acc_fence(acc[tm][tn]);
            int n = C0 + wn + tn * 16 + l16;
#pragma unroll
            for (int r = 0; r < 4; ++r) {
                int m = R0 + wm + tm * 16 + quad * 4 + r;
                float v = c[r];
                if (EPI == 0) {
                    v = silu_f(BNCF * (v + bias[n]));
                    v = silu_f(BNCF * (v * dww[n] + dwb[n]));
                } else if (EPI == 1) {
                    v = silu_f(BNCF * (v + bias[n]));
                    v = silu_f(BNCF * v);
                    v = silu_f(BNCF * (v * dww[n] + dwb[n]));
                } else if (EPI == 2) {
                    v = silu_f(BNCF * (v + bias[n]));
                    v = BNCF * v;
                } else {
                    v = BNCF * (v + bias[n]);
                    v = silu_f(v + res[(long)m * 128 + n]);
                }
                if (OD == 0)
                    ((u16*)Ov)[(long)m * Nn + n] = f2b(v);
                else
                    ((float*)Ov)[(long)m * Nn + n] = v;
            }
        }
    }
}

// ---------------------------------------------------------------- launcher
extern "C" void kernel_launch(void* const* d_in, const int* in_sizes, int n_in,
                              void* d_out, int out_size, void* d_ws, size_t ws_size,
                              hipStream_t stream) {
    const float* pos   = (const float*)d_in[0];
    const float* refl  = (const float*)d_in[1];
    const float* sfv   = (const float*)d_in[2];
    const int*   batch = (const int*)d_in[3];
    const int*   idxp  = (const int*)d_in[4];
    const int*   colp  = (const int*)d_in[5];
    const float* s_g  = (const float*)d_in[7];
    const float* s_b  = (const float*)d_in[8];
    const float* s_w1 = (const float*)d_in[9];
    const float* s_b1 = (const float*)d_in[10];
    const float* s_w2 = (const float*)d_in[11];
    const float* s_b2 = (const float*)d_in[12];
    const float* lkw  = (const float*)d_in[13];
    const float* lkb  = (const float*)d_in[14];
    const float* lng  = (const float*)d_in[15];
    const float* lnb  = (const float*)d_in[16];
    const float* l_w1 = (const float*)d_in[17];
    const float* l_b1 = (const float*)d_in[18];
    const float* l_w2 = (const float*)d_in[19];
    const float* l_b2 = (const float*)d_in[20];
    const float* expw = (const float*)d_in[21];
    const float* expb = (const float*)d_in[22];
    const float* dw1w = (const float*)d_in[23];
    const float* dw1b = (const float*)d_in[24];
    const float* pw1w = (const float*)d_in[25];
    const float* pw1b = (const float*)d_in[26];
    const float* dw2w = (const float*)d_in[27];
    const float* dw2b = (const float*)d_in[28];
    const float* pw2w = (const float*)d_in[29];
    const float* pw2b = (const float*)d_in[30];
    const float* prjw = (const float*)d_in[31];
    const float* prjb = (const float*)d_in[32];

    char* ws = (char*)d_ws;
    float* cent  = (float*)(ws + 0);                  // 64 B
    float* sfeat = (float*)(ws + 64);                 // M*3*4
    float* agg   = (float*)(ws + 393280);             // M*128*4 f32
    u16*   aggb  = (u16*)(ws + 17170496);             // M*128*2 bf16
    u16*   u1    = (u16*)(ws + 25559104);             // M*512*2
    u16*   u2    = (u16*)(ws + 59113536);             // M*512*2
    u16*   xf    = (u16*)(ws + 59113536);             // N*32*2 (aliases u2; dead before u2 written)
    u16*   expwt = (u16*)(ws + 92667968);             // 512*128*2
    u16*   pw1t  = (u16*)(ws + 92799040);             // 512*512*2
    u16*   pw2t  = (u16*)(ws + 93323328);             // 512*512*2
    u16*   prjt  = (u16*)(ws + 93847616);             // 128*512*2
    u16*   lw1t  = (u16*)(ws + 93978688);             // 64*64*2   = 8192
    u16*   lw2t  = (u16*)(ws + 93986880);             // 128*64*2  = 16384
    u16*   sw1t  = (u16*)(ws + 94003264);             // 64*128*2  = 16384
    u16*   sw2t  = (u16*)(ws + 94019648);             // 32*64*2   = 4096

    k_prep<<<2648, 256, 0, stream>>>(expw, expwt, pw1w, pw1t, pw2w, pw2t,
                                     prjw, prjt, l_w1, lw1t, l_w2, lw2t,
                                     s_w1, sw1t, s_w2, sw2t);

    hipMemsetAsync(cent, 0, 64, stream);
    k_centers<<<512, 256, 0, stream>>>(pos, sfv, batch, cent);
    k_stem<<<1024, 256, 0, stream>>>(pos, refl, sfv, batch, cent, s_g, s_b,
                                     sw1t, s_b1, sw2t, s_b2, xf);
    k_sfeat<<<128, 256, 0, stream>>>(pos, idxp, colp, lkw, lkb, lng, lnb, sfeat);
    k_edge<<<4096, 256, 0, stream>>>(pos, refl, idxp, colp, xf, sfeat,
                                     lw1t, l_b1, lw2t, l_b2, agg, aggb);

    dim3 blk(256);
    k_mgemm<0, 0><<<dim3(4, 256), blk, 0, stream>>>(aggb, expwt, expb, dw1w, dw1b,
                                                    nullptr, u1, 128, 512);
    k_mgemm<1, 0><<<dim3(4, 256), blk, 0, stream>>>(u1, pw1t, pw1b, dw2w, dw2b,
                                                    nullptr, u2, 512, 512);
    k_mgemm<2, 0><<<dim3(4, 256), blk, 0, stream>>>(u2, pw2t, pw2b, nullptr, nullptr,
                                                    nullptr, u1, 512, 512);
    k_mgemm<3, 1><<<dim3(1, 256), blk, 0, stream>>>(u1, prjt, prjb, nullptr, nullptr,
                                                    agg, d_out, 512, 128);
}

// Round 11
// 376.457 us; speedup vs baseline: 2.9986x; 1.1291x over previous
//
#include <hip/hip_runtime.h>

typedef unsigned short u16;
typedef unsigned int   u32;
typedef __attribute__((ext_vector_type(8))) u16  u16x8;
typedef __attribute__((ext_vector_type(4))) float f32x4;

#define N_PTS   131072
#define M_PTS   32768
#define BNCF    0.9999950000374997f

__device__ __forceinline__ float b2f(u16 u) {
    u32 x = ((u32)u) << 16;
    float f;
    __builtin_memcpy(&f, &x, 4);
    return f;
}
__device__ __forceinline__ u16 f2b(float f) {
    u32 x;
    __builtin_memcpy(&x, &f, 4);
    u32 r = x + 0x7fffu + ((x >> 16) & 1u);
    return (u16)(r >> 16);
}
__device__ __forceinline__ float silu_f(float x) {
    return x / (1.0f + __expf(-x));
}

__device__ __forceinline__ f32x4 mfma_bf16(u16x8 a, u16x8 b, f32x4 c) {
    asm volatile("v_mfma_f32_16x16x32_bf16 %0, %1, %2, %0"
                 : "+v"(c) : "v"(a), "v"(b));
    return c;
}
// MAI->VALU wait-state guard.
__device__ __forceinline__ f32x4 acc_fence(f32x4 c) {
    asm volatile("s_nop 7\n\ts_nop 7\n\ts_nop 3" : "+v"(c));
    return c;
}

// async global->LDS, 16B per lane. LDS dest = wave-uniform base + lane*16.
__device__ __forceinline__ void cp_glds16(const u16* g, u16* l) {
    typedef const __attribute__((address_space(1))) u32* gp1_t;
    typedef __attribute__((address_space(3))) u32* lp3_t;
    __builtin_amdgcn_global_load_lds((gp1_t)(unsigned long long)g,
                                     (lp3_t)(unsigned long long)l, 16, 0, 0);
}

// ---------------------------------------------------------------- all weight transposes in ONE dispatch
__global__ __launch_bounds__(256) void k_prep(const float* __restrict__ expw, u16* __restrict__ expwt,
                                              const float* __restrict__ pw1w, u16* __restrict__ pw1t,
                                              const float* __restrict__ pw2w, u16* __restrict__ pw2t,
                                              const float* __restrict__ prjw, u16* __restrict__ prjt,
                                              const float* __restrict__ lw1,  u16* __restrict__ lw1t,
                                              const float* __restrict__ lw2,  u16* __restrict__ lw2t,
                                              const float* __restrict__ sw1,  u16* __restrict__ sw1t,
                                              const float* __restrict__ sw2,  u16* __restrict__ sw2t) {
    int idx = blockIdx.x * 256 + threadIdx.x;
    const float* W; u16* O; int K, Kp, Nn;
    if (idx < 65536)                 { W = expw; O = expwt; K = 128; Kp = 128; Nn = 512; }
    else if ((idx -= 65536) < 262144){ W = pw1w; O = pw1t;  K = 512; Kp = 512; Nn = 512; }
    else if ((idx -= 262144) < 262144){ W = pw2w; O = pw2t; K = 512; Kp = 512; Nn = 512; }
    else if ((idx -= 262144) < 65536){ W = prjw; O = prjt;  K = 512; Kp = 512; Nn = 128; }
    else if ((idx -= 65536) < 4096)  { W = lw1;  O = lw1t;  K = 39;  Kp = 64;  Nn = 64;  }
    else if ((idx -= 4096) < 8192)   { W = lw2;  O = lw2t;  K = 64;  Kp = 64;  Nn = 128; }
    else if ((idx -= 8192) < 8192)   { W = sw1;  O = sw1t;  K = 97;  Kp = 128; Nn = 64;  }
    else if ((idx -= 8192) < 2048)   { W = sw2;  O = sw2t;  K = 64;  Kp = 64;  Nn = 32;  }
    else return;
    int n = idx / Kp, k = idx % Kp;
    O[idx] = (k < K) ? f2b(W[(long)k * Nn + n]) : (u16)0;
}

// ---------------------------------------------------------------- centers
__global__ __launch_bounds__(256) void k_centers(const float* __restrict__ pos,
                                                 const float* __restrict__ sfv,
                                                 const int* __restrict__ batch,
                                                 float* __restrict__ acc) {
    __shared__ float ls[16];
    int t = threadIdx.x;
    if (t < 16) ls[t] = 0.0f;
    __syncthreads();
    int i = blockIdx.x * 256 + t;
    if (i < N_PTS) {
        int b = batch[i];
        float inv = 1.0f / sfv[b];
        atomicAdd(&ls[b * 4 + 0], pos[i * 3 + 0] * inv);
        atomicAdd(&ls[b * 4 + 1], pos[i * 3 + 1] * inv);
        atomicAdd(&ls[b * 4 + 2], pos[i * 3 + 2] * inv);
        atomicAdd(&ls[b * 4 + 3], 1.0f);
    }
    __syncthreads();
    if (t < 16) atomicAdd(&acc[t], ls[t]);
}

// ---------------------------------------------------------------- stem (MFMA)
__global__ __launch_bounds__(256) void k_stem(const float* __restrict__ pos,
                                              const float* __restrict__ refl,
                                              const float* __restrict__ sfv,
                                              const int* __restrict__ batch,
                                              const float* __restrict__ cacc,
                                              const float* __restrict__ g,
                                              const float* __restrict__ bb,
                                              const u16* __restrict__ w1t,   // [64][128] bf16 (zero pad k>=97)
                                              const float* __restrict__ b1,
                                              const u16* __restrict__ w2t,   // [32][64] bf16
                                              const float* __restrict__ b2,
                                              u16* __restrict__ xout) {
    __shared__ u16 xs[128][136];
    __shared__ u16 hb[128][72];
    __shared__ u16 w1s[64][136];
    __shared__ u16 w2s[32][72];
    __shared__ float b1s[64];
    __shared__ float b2s[32];
    const float FREQS[16] = {
        1.0f, 0.31622776601683794f, 0.1f, 0.031622776601683791f,
        0.01f, 0.0031622776601683794f, 0.001f, 0.00031622776601683794f,
        0.0001f, 3.1622776601683795e-05f, 1e-05f, 3.1622776601683796e-06f,
        1e-06f, 3.1622776601683797e-07f, 1e-07f, 3.1622776601683792e-08f};
    int t = threadIdx.x;
    int wave = t >> 6, lane = t & 63;
    int quad = lane >> 4, l16 = lane & 15;
    int mt0 = wave * 2;

    // zero ALL of xs: 128*136 u16 = 2176 uint4
    for (int u = t; u < 2176; u += 256) ((uint4*)xs)[u] = (uint4){0, 0, 0, 0};
    for (int u = t; u < 1024; u += 256) {
        int row = u >> 4, c8 = (u & 15) * 8;
        *(uint4*)(&w1s[row][c8]) = *(const uint4*)(w1t + row * 128 + c8);
    }
    {
        int row = t >> 3, c8 = (t & 7) * 8;
        *(uint4*)(&w2s[row][c8]) = *(const uint4*)(w2t + row * 64 + c8);
    }
    if (t < 64) b1s[t] = b1[t];
    if (t < 32) b2s[t] = b2[t];
    __syncthreads();

    if (t < 128) {
        int i = blockIdx.x * 128 + t;
        int b = batch[i];
        float s = 1.0f / sfv[b];
        float cnt = fmaxf(cacc[b * 4 + 3], 1.0f);
        float npv[3];
#pragma unroll
        for (int d = 0; d < 3; ++d)
            npv[d] = pos[i * 3 + d] * s - cacc[b * 4 + d] / cnt;

        float sum = 0.0f, sq = 0.0f;
#pragma unroll
        for (int d = 0; d < 3; ++d) {
#pragma unroll
            for (int f = 0; f < 16; ++f) {
                float a = npv[d] * FREQS[f];
                float sv, cv;
                __sincosf(a, &sv, &cv);
                sum += sv + cv;
                sq += sv * sv + cv * cv;
                xs[t][d * 32 + f] = f2b(sv);
                xs[t][d * 32 + 16 + f] = f2b(cv);
            }
        }
        float rf = refl[i];
        sum += rf;
        sq += rf * rf;
        xs[t][96] = f2b(rf);

        float m = sum * (1.0f / 97.0f);
        float var = sq * (1.0f / 97.0f) - m * m;
        float rstd = rsqrtf(fmaxf(var, 0.0f) + 1e-5f);
        for (int k = 0; k < 97; ++k) {
            float v = b2f(xs[t][k]);
            xs[t][k] = f2b((v - m) * rstd * g[k] + bb[k]);
        }
    }
    __syncthreads();

    {
        f32x4 acc[2][4];
#pragma unroll
        for (int i = 0; i < 2; ++i)
#pragma unroll
            for (int j = 0; j < 4; ++j) acc[i][j] = (f32x4){0.f, 0.f, 0.f, 0.f};
#pragma unroll
        for (int kk = 0; kk < 128; kk += 32) {
            u16x8 af[2], bfr[4];
#pragma unroll
            for (int i = 0; i < 2; ++i)
                af[i] = *(const u16x8*)(&xs[(mt0 + i) * 16 + l16][kk + quad * 8]);
#pragma unroll
            for (int j = 0; j < 4; ++j)
                bfr[j] = *(const u16x8*)(&w1s[j * 16 + l16][kk + quad * 8]);
#pragma unroll
            for (int i = 0; i < 2; ++i)
#pragma unroll
                for (int j = 0; j < 4; ++j)
                    acc[i][j] = mfma_bf16(af[i], bfr[j], acc[i][j]);
        }
#pragma unroll
        for (int i = 0; i < 2; ++i)
#pragma unroll
            for (int j = 0; j < 4; ++j) {
                f32x4 c = acc_fence(acc[i][j]);
                int n = j * 16 + l16;
#pragma unroll
                for (int r = 0; r < 4; ++r)
                    hb[(mt0 + i) * 16 + quad * 4 + r][n] =
                        f2b(silu_f(BNCF * (c[r] + b1s[n])));
            }
    }
    __syncthreads();

    {
        f32x4 acc[2][2];
#pragma unroll
        for (int i = 0; i < 2; ++i)
#pragma unroll
            for (int j = 0; j < 2; ++j) acc[i][j] = (f32x4){0.f, 0.f, 0.f, 0.f};
#pragma unroll
        for (int kk = 0; kk < 64; kk += 32) {
            u16x8 af[2], bfr[2];
#pragma unroll
            for (int i = 0; i < 2; ++i)
                af[i] = *(const u16x8*)(&hb[(mt0 + i) * 16 + l16][kk + quad * 8]);
#pragma unroll
            for (int j = 0; j < 2; ++j)
                bfr[j] = *(const u16x8*)(&w2s[j * 16 + l16][kk + quad * 8]);
#pragma unroll
            for (int i = 0; i < 2; ++i)
#pragma unroll
                for (int j = 0; j < 2; ++j)
                    acc[i][j] = mfma_bf16(af[i], bfr[j], acc[i][j]);
        }
#pragma unroll
        for (int i = 0; i < 2; ++i)
#pragma unroll
            for (int j = 0; j < 2; ++j) {
                f32x4 c = acc_fence(acc[i][j]);
                int n = j * 16 + l16;
#pragma unroll
                for (int r = 0; r < 4; ++r) {
                    int m = (mt0 + i) * 16 + quad * 4 + r;
                    long ig = (long)blockIdx.x * 128 + m;
                    xout[ig * 32 + n] = f2b(silu_f(BNCF * (c[r] + b2s[n])));
                }
            }
    }
}

// ---------------------------------------------------------------- sfeat
__global__ __launch_bounds__(256) void k_sfeat(const float* __restrict__ pos,
                                               const int* __restrict__ idxp,
                                               const int* __restrict__ colp,
                                               const float* __restrict__ lkw,
                                               const float* __restrict__ lkb,
                                               const float* __restrict__ lng,
                                               const float* __restrict__ lnb,
                                               float* __restrict__ sfeat) {
    int r = blockIdx.x * 256 + threadIdx.x;
    if (r >= M_PTS) return;
    int ci = idxp[r];
    float cx = pos[ci * 3 + 0];
    float cy = pos[ci * 3 + 1];
    float cz = pos[ci * 3 + 2];
    float dsx = 0.0f, dsy = 0.0f, dsz = 0.0f;
    for (int e = 0; e < 16; ++e) {
        int c = colp[r * 16 + e];
        float dx = pos[c * 3 + 0] - cx;
        float dy = pos[c * 3 + 1] - cy;
        float dz = pos[c * 3 + 2] - cz;
        float nrm = sqrtf(dx * dx + dy * dy + dz * dz);
        float inv = 1.0f / (nrm + 1e-8f);
        dsx += dx * inv;
        dsy += dy * inv;
        dsz += dz * inv;
    }
    const float S3 = 0.57735026918962576f;
    const float sx[8] = {1, -1, 1, 1, -1, -1, 1, -1};
    const float sy[8] = {1, 1, -1, 1, -1, 1, -1, -1};
    const float sz[8] = {1, 1, 1, -1, 1, -1, -1, -1};
    float sc[3] = {lkb[0], lkb[1], lkb[2]};
#pragma unroll
    for (int j = 0; j < 8; ++j) {
        float nb = (sx[j] * dsx + sy[j] * dsy + sz[j] * dsz) * (S3 * (1.0f / 16.0f));
        sc[0] += nb * lkw[j * 3 + 0];
        sc[1] += nb * lkw[j * 3 + 1];
        sc[2] += nb * lkw[j * 3 + 2];
    }
    float m = (sc[0] + sc[1] + sc[2]) * (1.0f / 3.0f);
    float v = ((sc[0] - m) * (sc[0] - m) + (sc[1] - m) * (sc[1] - m) +
               (sc[2] - m) * (sc[2] - m)) * (1.0f / 3.0f);
    float rstd = rsqrtf(fmaxf(v, 0.0f) + 1e-5f);
#pragma unroll
    for (int c = 0; c < 3; ++c)
        sfeat[r * 3 + c] = (sc[c] - m) * rstd * lng[c] + lnb[c];
}

// ---------------------------------------------------------------- edge MLP + segment max (MFMA)
__global__ __launch_bounds__(256) void k_edge(const float* __restrict__ pos,
                                              const float* __restrict__ refl,
                                              const int* __restrict__ idxp,
                                              const int* __restrict__ colp,
                                              const u16* __restrict__ xfeat,
                                              const float* __restrict__ sfeat,
                                              const u16* __restrict__ w1t,
                                              const float* __restrict__ b1,
                                              const u16* __restrict__ w2t,
                                              const float* __restrict__ b2,
                                              float* __restrict__ agg,
                                              u16* __restrict__ aggb) {
    __shared__ u16 uni16[128 * 72];   // msg bf16, then w2t
    __shared__ u16 hs[128 * 72];
    __shared__ u16 w1s[64 * 72];
    __shared__ float b1s[64];
    __shared__ float b2s[128];
    int t = threadIdx.x;
    int r0 = blockIdx.x * 8;
    long e0 = (long)r0 * 16;
    int wave = t >> 6, lane = t & 63;
    int quad = lane >> 4, l16 = lane & 15;
    int mt0 = wave * 2;

    for (int u = t; u < 512; u += 256) {
        int row = u >> 3, c8 = (u & 7) * 8;
        *(uint4*)(&w1s[row * 72 + c8]) = *(const uint4*)(w1t + row * 64 + c8);
    }
    if (t < 64) b1s[t] = b1[t];
    if (t < 128) b2s[t] = b2[t];

    for (int u = t; u < 512; u += 256) {
        int e = u >> 2, seg = u & 3;
        int c = colp[e0 + e];
        uint4 d = *(const uint4*)(xfeat + (long)c * 32 + seg * 8);
        *(uint4*)(&uni16[e * 72 + seg * 8]) = d;
    }
    if (t < 128) {
        int e = t;
        int r = r0 + (e >> 4);
        int c = colp[e0 + e];
        int ci = idxp[r];
        u16 tmp[8];
        tmp[0] = f2b(pos[c * 3 + 0] - pos[ci * 3 + 0]);
        tmp[1] = f2b(pos[c * 3 + 1] - pos[ci * 3 + 1]);
        tmp[2] = f2b(pos[c * 3 + 2] - pos[ci * 3 + 2]);
        tmp[3] = f2b(refl[c] - refl[ci]);
        tmp[4] = f2b(sfeat[r * 3 + 0]);
        tmp[5] = f2b(sfeat[r * 3 + 1]);
        tmp[6] = f2b(sfeat[r * 3 + 2]);
        tmp[7] = 0;
        *(uint4*)(&uni16[e * 72 + 32]) = *(uint4*)tmp;
        uint4 z = {0, 0, 0, 0};
        *(uint4*)(&uni16[e * 72 + 40]) = z;
        *(uint4*)(&uni16[e * 72 + 48]) = z;
        *(uint4*)(&uni16[e * 72 + 56]) = z;
    }
    __syncthreads();

    {
        f32x4 acc[2][4];
#pragma unroll
        for (int i = 0; i < 2; ++i)
#pragma unroll
            for (int j = 0; j < 4; ++j) acc[i][j] = (f32x4){0.f, 0.f, 0.f, 0.f};
#pragma unroll
        for (int kk = 0; kk < 64; kk += 32) {
            u16x8 af[2], bfr[4];
#pragma unroll
            for (int i = 0; i < 2; ++i)
                af[i] = *(const u16x8*)(&uni16[((mt0 + i) * 16 + l16) * 72 + kk + quad * 8]);
#pragma unroll
            for (int j = 0; j < 4; ++j)
                bfr[j] = *(const u16x8*)(&w1s[(j * 16 + l16) * 72 + kk + quad * 8]);
#pragma unroll
            for (int i = 0; i < 2; ++i)
#pragma unroll
                for (int j = 0; j < 4; ++j)
                    acc[i][j] = mfma_bf16(af[i], bfr[j], acc[i][j]);
        }
#pragma unroll
        for (int i = 0; i < 2; ++i)
#pragma unroll
            for (int j = 0; j < 4; ++j) {
                f32x4 c = acc_fence(acc[i][j]);
                int n = j * 16 + l16;
#pragma unroll
                for (int r = 0; r < 4; ++r) {
                    float v = silu_f(BNCF * (c[r] + b1s[n]));
                    hs[((mt0 + i) * 16 + quad * 4 + r) * 72 + n] = f2b(v);
                }
            }
    }
    __syncthreads();

    for (int u = t; u < 1024; u += 256) {
        int row = u >> 3, c8 = (u & 7) * 8;
        *(uint4*)(&uni16[row * 72 + c8]) = *(const uint4*)(w2t + row * 64 + c8);
    }
    __syncthreads();

    {
        f32x4 acc[2][8];
#pragma unroll
        for (int i = 0; i < 2; ++i)
#pragma unroll
            for (int j = 0; j < 8; ++j) acc[i][j] = (f32x4){0.f, 0.f, 0.f, 0.f};
#pragma unroll
        for (int kk = 0; kk < 64; kk += 32) {
            u16x8 af[2], bfr[8];
#pragma unroll
            for (int i = 0; i < 2; ++i)
                af[i] = *(const u16x8*)(&hs[((mt0 + i) * 16 + l16) * 72 + kk + quad * 8]);
#pragma unroll
            for (int j = 0; j < 8; ++j)
                bfr[j] = *(const u16x8*)(&uni16[(j * 16 + l16) * 72 + kk + quad * 8]);
#pragma unroll
            for (int i = 0; i < 2; ++i)
#pragma unroll
                for (int j = 0; j < 8; ++j)
                    acc[i][j] = mfma_bf16(af[i], bfr[j], acc[i][j]);
        }
        // max_e silu(x_e) == max(silu(max x), silu(min x)) — silu quasiconvex.
#pragma unroll
        for (int i = 0; i < 2; ++i) {
            int rg = r0 + mt0 + i;
#pragma unroll
            for (int j = 0; j < 8; ++j) {
                f32x4 c = acc_fence(acc[i][j]);
                int n = j * 16 + l16;
                float mx = fmaxf(fmaxf(c[0], c[1]), fmaxf(c[2], c[3]));
                float mn = fminf(fminf(c[0], c[1]), fminf(c[2], c[3]));
                mx = fmaxf(mx, __shfl_xor(mx, 16));
                mx = fmaxf(mx, __shfl_xor(mx, 32));
                mn = fminf(mn, __shfl_xor(mn, 16));
                mn = fminf(mn, __shfl_xor(mn, 32));
                if (quad == 0) {
                    float v = fmaxf(silu_f(BNCF * (mx + b2s[n])),
                                    silu_f(BNCF * (mn + b2s[n])));
                    agg[(long)rg * 128 + n] = v;
                    aggb[(long)rg * 128 + n] = f2b(v);
                }
            }
        }
    }
}

// ---------------------------------------------------------------- MFMA GEMM (async staging + XOR swizzle)
// LDS tiles unpadded [128][64] u16. LDS (row, chunk c) holds global chunk c^(row&7).
template <int EPI, int OD>
__global__ __launch_bounds__(256) void k_mgemm(const u16* __restrict__ A,
                                               const u16* __restrict__ Bt,
                                               const float* __restrict__ bias,
                                               const float* __restrict__ dww,
                                               const float* __restrict__ dwb,
                                               const float* __restrict__ res,
                                               void* __restrict__ Ov,
                                               int K, int Nn) {
    __shared__ u16 As[128 * 64];
    __shared__ u16 Bs[128 * 64];
    int t = threadIdx.x;
    int wave = t >> 6, lane = t & 63;
    int quad = lane >> 4, l16 = lane & 15;
    int R0 = blockIdx.y * 128, C0 = blockIdx.x * 128;
    int wm = (wave & 1) * 64, wn = (wave >> 1) * 64;

    int srow = (lane >> 3);                 // 0..7 within 8-row group
    int sch  = lane & 7;                    // 16B chunk 0..7

    f32x4 acc[4][4];
#pragma unroll
    for (int i = 0; i < 4; ++i)
#pragma unroll
        for (int j = 0; j < 4; ++j) acc[i][j] = (f32x4){0.f, 0.f, 0.f, 0.f};

    for (int k0 = 0; k0 < K; k0 += 64) {
#pragma unroll
        for (int it = 0; it < 4; ++it) {
            int base = wave * 32 + it * 8;
            int row = base + srow;
            int gch = (sch ^ (row & 7)) << 3;   // swizzled source chunk
            cp_glds16(A  + (long)(R0 + row) * K + k0 + gch, &As[base * 64]);
            cp_glds16(Bt + (long)(C0 + row) * K + k0 + gch, &Bs[base * 64]);
        }
        __syncthreads();
#pragma unroll
        for (int kk = 0; kk < 64; kk += 32) {
            int kb = kk >> 3;                    // 0 or 4
            u16x8 af[4], bfr[4];
#pragma unroll
            for (int tm = 0; tm < 4; ++tm) {
                int r = wm + tm * 16 + l16;
                af[tm] = *(const u16x8*)(&As[r * 64 + (((kb + quad) ^ (r & 7)) << 3)]);
            }
#pragma unroll
            for (int tn = 0; tn < 4; ++tn) {
                int r = wn + tn * 16 + l16;
                bfr[tn] = *(const u16x8*)(&Bs[r * 64 + (((kb + quad) ^ (r & 7)) << 3)]);
            }
#pragma unroll
            for (int tm = 0; tm < 4; ++tm)
#pragma unroll
                for (int tn = 0; tn < 4; ++tn)
                    acc[tm][tn] = mfma_bf16(af[tm], bfr[tn], acc[tm][tn]);
        }
        __syncthreads();
    }

#pragma unroll
    for (int tm = 0; tm < 4; ++tm) {
#pragma unroll
        for (int tn = 0; tn < 4; ++tn) {
            f32x4 c = acc_fence(acc[tm][tn]);
            int n = C0 + wn + tn * 16 + l16;
#pragma unroll
            for (int r = 0; r < 4; ++r) {
                int m = R0 + wm + tm * 16 + quad * 4 + r;
                float v = c[r];
                if (EPI == 0) {
                    v = silu_f(BNCF * (v + bias[n]));
                    v = silu_f(BNCF * (v * dww[n] + dwb[n]));
                } else if (EPI == 1) {
                    v = silu_f(BNCF * (v + bias[n]));
                    v = silu_f(BNCF * v);
                    v = silu_f(BNCF * (v * dww[n] + dwb[n]));
                } else if (EPI == 2) {
                    v = silu_f(BNCF * (v + bias[n]));
                    v = BNCF * v;
                } else {
                    v = BNCF * (v + bias[n]);
                    v = silu_f(v + res[(long)m * 128 + n]);
                }
                if (OD == 0)
                    ((u16*)Ov)[(long)m * Nn + n] = f2b(v);
                else
                    ((float*)Ov)[(long)m * Nn + n] = v;
            }
        }
    }
}

// ---------------------------------------------------------------- launcher
extern "C" void kernel_launch(void* const* d_in, const int* in_sizes, int n_in,
                              void* d_out, int out_size, void* d_ws, size_t ws_size,
                              hipStream_t stream) {
    const float* pos   = (const float*)d_in[0];
    const float* refl  = (const float*)d_in[1];
    const float* sfv   = (const float*)d_in[2];
    const int*   batch = (const int*)d_in[3];
    const int*   idxp  = (const int*)d_in[4];
    const int*   colp  = (const int*)d_in[5];
    const float* s_g  = (const float*)d_in[7];
    const float* s_b  = (const float*)d_in[8];
    const float* s_w1 = (const float*)d_in[9];
    const float* s_b1 = (const float*)d_in[10];
    const float* s_w2 = (const float*)d_in[11];
    const float* s_b2 = (const float*)d_in[12];
    const float* lkw  = (const float*)d_in[13];
    const float* lkb  = (const float*)d_in[14];
    const float* lng  = (const float*)d_in[15];
    const float* lnb  = (const float*)d_in[16];
    const float* l_w1 = (const float*)d_in[17];
    const float* l_b1 = (const float*)d_in[18];
    const float* l_w2 = (const float*)d_in[19];
    const float* l_b2 = (const float*)d_in[20];
    const float* expw = (const float*)d_in[21];
    const float* expb = (const float*)d_in[22];
    const float* dw1w = (const float*)d_in[23];
    const float* dw1b = (const float*)d_in[24];
    const float* pw1w = (const float*)d_in[25];
    const float* pw1b = (const float*)d_in[26];
    const float* dw2w = (const float*)d_in[27];
    const float* dw2b = (const float*)d_in[28];
    const float* pw2w = (const float*)d_in[29];
    const float* pw2b = (const float*)d_in[30];
    const float* prjw = (const float*)d_in[31];
    const float* prjb = (const float*)d_in[32];

    char* ws = (char*)d_ws;
    float* cent  = (float*)(ws + 0);                  // 64 B
    float* sfeat = (float*)(ws + 64);                 // M*3*4
    float* agg   = (float*)(ws + 393280);             // M*128*4 f32
    u16*   aggb  = (u16*)(ws + 17170496);             // M*128*2 bf16
    u16*   u1    = (u16*)(ws + 25559104);             // M*512*2
    u16*   u2    = (u16*)(ws + 59113536);             // M*512*2
    u16*   xf    = (u16*)(ws + 59113536);             // N*32*2 (aliases u2; dead before u2 written)
    u16*   expwt = (u16*)(ws + 92667968);             // 512*128*2
    u16*   pw1t  = (u16*)(ws + 92799040);             // 512*512*2
    u16*   pw2t  = (u16*)(ws + 93323328);             // 512*512*2
    u16*   prjt  = (u16*)(ws + 93847616);             // 128*512*2
    u16*   lw1t  = (u16*)(ws + 93978688);             // 64*64*2   = 8192
    u16*   lw2t  = (u16*)(ws + 93986880);             // 128*64*2  = 16384
    u16*   sw1t  = (u16*)(ws + 94003264);             // 64*128*2  = 16384
    u16*   sw2t  = (u16*)(ws + 94019648);             // 32*64*2   = 4096

    k_prep<<<2648, 256, 0, stream>>>(expw, expwt, pw1w, pw1t, pw2w, pw2t,
                                     prjw, prjt, l_w1, lw1t, l_w2, lw2t,
                                     s_w1, sw1t, s_w2, sw2t);

    hipMemsetAsync(cent, 0, 64, stream);
    k_centers<<<512, 256, 0, stream>>>(pos, sfv, batch, cent);
    k_stem<<<1024, 256, 0, stream>>>(pos, refl, sfv, batch, cent, s_g, s_b,
                                     sw1t, s_b1, sw2t, s_b2, xf);
    k_sfeat<<<128, 256, 0, stream>>>(pos, idxp, colp, lkw, lkb, lng, lnb, sfeat);
    k_edge<<<4096, 256, 0, stream>>>(pos, refl, idxp, colp, xf, sfeat,
                                     lw1t, l_b1, lw2t, l_b2, agg, aggb);

    dim3 blk(256);
    k_mgemm<0, 0><<<dim3(4, 256), blk, 0, stream>>>(aggb, expwt, expb, dw1w, dw1b,
                                                    nullptr, u1, 128, 512);
    k_mgemm<1, 0><<<dim3(4, 256), blk, 0, stream>>>(u1, pw1t, pw1b, dw2w, dw2b,
                                                    nullptr, u2, 512, 512);
    k_mgemm<2, 0><<<dim3(4, 256), blk, 0, stream>>>(u2, pw2t, pw2b, nullptr, nullptr,
                                                    nullptr, u1, 512, 512);
    k_mgemm<3, 1><<<dim3(1, 256), blk, 0, stream>>>(u1, prjt, prjb, nullptr, nullptr,
                                                    agg, d_out, 512, 128);
}